// Round 2
// baseline (3171.139 us; speedup 1.0000x reference)
//
#include <hip/hip_runtime.h>
#include <hip/hip_bf16.h>

typedef __hip_bfloat16 bf16;

__device__ __forceinline__ float b2f(bf16 v){ return __bfloat162float(v); }
__device__ __forceinline__ float sigm(float x){ return 1.0f/(1.0f+__expf(-x)); }
__device__ __forceinline__ float tanhc(float x){
  x = fminf(15.0f, fmaxf(-15.0f, x));
  float e = __expf(2.0f*x);
  return (e-1.0f)/(e+1.0f);
}

// ---------------------------------------------------------------------------
// ws layout (float offsets)
// ---------------------------------------------------------------------------
#define WS_SMALL   0          // 262144 (converted small weights, see offs below)
#define WS_FLAG    262144     // 1 int (1 = inputs are f32, 0 = inputs are bf16)
#define WS_H       262208
#define WS_C       524352
#define WS_M       786496
#define WS_HNEW    1048640
#define WS_WRE     1310784    // 294912 reformatted conv weights
#define WS_QB      1605696    // 65536
#define WS_KHB     1671232
#define WS_KMB     1736768
#define WS_VHB     1802304    // 262144
#define WS_VMB     2064448
#define WS_ATT     2326592    // 4194304 (single branch, reused)
#define WS_ZCAT    6520896    // 524288
// small-weight offsets inside WS_SMALL
#define O_CB    0
#define O_WCI   256
#define O_WCF   65792
#define O_WCO   131328
#define O_QW    196864
#define O_QB    197888
#define O_KW    197904
#define O_KB    198928
#define O_K2W   198944
#define O_K2B   199968
#define O_VW    199984
#define O_VB    204080
#define O_V2W   204144
#define O_V2B   208240
#define O_ZW    208304
#define O_ZB    224688
#define O_MW    224816
#define O_MB    261680

// ---------------------------------------------------------------------------
// dtype probe: read first 256 u32 words of X; low-16-as-bf16 of f32 data is
// exponent noise (~45% |v|>1e4 or NaN); of bf16 data it is a sane normal.
// ---------------------------------------------------------------------------
__global__ void k_probe(const unsigned int* __restrict__ Xu, int* __restrict__ flag){
  __shared__ int cnt;
  if (threadIdx.x == 0) cnt = 0;
  __syncthreads();
  unsigned int u = Xu[threadIdx.x];
  float f = __uint_as_float((u & 0xffffu) << 16);
  int bad = (fabsf(f) <= 1e4f) ? 0 : 1;   // catches NaN too
  atomicAdd(&cnt, bad);
  __syncthreads();
  if (threadIdx.x == 0) *flag = (cnt > 16) ? 1 : 0;
}

// ---------------------------------------------------------------------------
// convert the 18 small inputs into f32 copies in ws
// ---------------------------------------------------------------------------
struct P18 { const void* p[18]; };

__global__ __launch_bounds__(256) void k_wconv(P18 pk, const int* __restrict__ flagp,
                                               float* __restrict__ dst){
  const int ns[18]   = {256,65536,65536,65536,1024,16,1024,16,1024,16,
                        4096,64,4096,64,16384,128,36864,192};
  const int offs[18] = {O_CB,O_WCI,O_WCF,O_WCO,O_QW,O_QB,O_KW,O_KB,O_K2W,O_K2B,
                        O_VW,O_VB,O_V2W,O_V2B,O_ZW,O_ZB,O_MW,O_MB};
  int y = blockIdx.y;
  int n = ns[y];
  int flag = *flagp;
  const void* src = pk.p[y];
  for (int i = blockIdx.x*256 + threadIdx.x; i < n; i += gridDim.x*256){
    float v = flag ? ((const float*)src)[i] : b2f(((const bf16*)src)[i]);
    dst[offs[y] + i] = v;
  }
}

// ---------------------------------------------------------------------------
// init: zero h,c,m (786432 floats) and reformat conv weights:
// wre[(o*9+p)*128 + ci] = conv_w[(o*128+ci)*9 + p]
// ---------------------------------------------------------------------------
__global__ __launch_bounds__(256) void k_init(const void* __restrict__ conv_w,
                                              const int* __restrict__ flagp,
                                              float* __restrict__ ws){
  int i = blockIdx.x*256 + threadIdx.x;
  int flag = *flagp;
  if (i < 786432) ws[WS_H + i] = 0.0f;
  if (i < 294912){
    int ci = i & 127;
    int rest = i >> 7;        // o*9 + p
    int p = rest % 9;
    int o = rest / 9;
    int si = (o*128 + ci)*9 + p;
    ws[WS_WRE + i] = flag ? ((const float*)conv_w)[si] : b2f(((const bf16*)conv_w)[si]);
  }
}

// ---------------------------------------------------------------------------
// conv 3x3 (128 -> 256ch) + peephole LSTM pointwise. Two 64-ci phases.
// grid (8 cgroups, 8 ygroups, 4 b), block 256 = 8cc x 4yl x 8xt (4 px each)
// LDS: 6 rows x 64 ci x 34 xp f32; row stride 2320 (16-word stagger -> 2-way)
// ---------------------------------------------------------------------------
#define RW 2320
__global__ __launch_bounds__(256) void k_conv_lstm(
  const int* __restrict__ flagp, const void* __restrict__ Xraw,
  const float* __restrict__ wre, const float* __restrict__ smalls,
  const float* __restrict__ hprev, float* __restrict__ cst,
  float* __restrict__ hnew, int t)
{
  __shared__ float lds[6*RW];
  int cg = blockIdx.x, yg = blockIdx.y, b = blockIdx.z;
  int tid = threadIdx.x;
  int flag = *flagp;
  int xt = tid & 7, yl = (tid>>3)&3, cl = tid>>5;
  int cc = cg*8 + cl;

  float acc[4][4];
  #pragma unroll
  for (int g=0; g<4; ++g){
    float bv = smalls[O_CB + g*64 + cc];
    acc[g][0]=bv; acc[g][1]=bv; acc[g][2]=bv; acc[g][3]=bv;
  }

  for (int ph = 0; ph < 2; ++ph){
    if (ph) __syncthreads();
    for (int idx = tid; idx < 6*64*34; idx += 256){
      int row = idx / 2176;
      int rem = idx - row*2176;
      int ci  = rem / 34;
      int xp  = rem - ci*34;
      int yin = yg*4 - 1 + row;
      int xin = xp - 1;
      float v = 0.0f;
      if (yin >= 0 && yin < 32 && xin >= 0 && xin < 32){
        if (ph == 0){
          int si = (((b*64+ci)*8 + t)*32 + yin)*32 + xin;
          v = flag ? ((const float*)Xraw)[si] : b2f(((const bf16*)Xraw)[si]);
        } else {
          v = hprev[((b*64 + ci)*32 + yin)*32 + xin];
        }
      }
      lds[row*RW + ci*36 + xp] = v;
    }
    __syncthreads();

    const float* wbase = wre + (size_t)cc*1152 + ph*64;
    for (int dy=0; dy<3; ++dy){
      const float* lrow = lds + (yl+dy)*RW;
      for (int ci4=0; ci4<16; ++ci4){
        float iv[4][6];
        #pragma unroll
        for (int j=0;j<4;++j){
          const float* lp = lrow + (ci4*4+j)*36 + xt*4;
          float4 a4 = *reinterpret_cast<const float4*>(lp);
          float2 a2 = *reinterpret_cast<const float2*>(lp+4);
          iv[j][0]=a4.x; iv[j][1]=a4.y; iv[j][2]=a4.z; iv[j][3]=a4.w;
          iv[j][4]=a2.x; iv[j][5]=a2.y;
        }
        #pragma unroll
        for (int dx=0; dx<3; ++dx){
          int p = dy*3+dx;
          #pragma unroll
          for (int g=0; g<4; ++g){
            const float4 w4 = *reinterpret_cast<const float4*>(wbase + (size_t)g*73728 + p*128 + ci4*4);
            #pragma unroll
            for (int px=0;px<4;++px){
              acc[g][px] += w4.x*iv[0][px+dx] + w4.y*iv[1][px+dx]
                          + w4.z*iv[2][px+dx] + w4.w*iv[3][px+dx];
            }
          }
        }
      }
    }
  }

  int y = yg*4 + yl, x0 = xt*4;
  int nbase = y*32 + x0;
  size_t sidx = ((size_t)(b*64+cc))*1024 + nbase;
  float4 c4 = *reinterpret_cast<const float4*>(cst + sidx);
  float cn[4], hn[4];
  #pragma unroll
  for (int px=0; px<4; ++px){
    float cprev = (&c4.x)[px];
    int wi = cc*1024 + nbase + px;
    float ig = sigm(acc[0][px] + smalls[O_WCI + wi]*cprev);
    float fg = sigm(acc[1][px] + smalls[O_WCF + wi]*cprev);
    float cnew = fg*cprev + ig*tanhc(acc[2][px]);
    float og = sigm(acc[3][px] + smalls[O_WCO + wi]*cnew);
    cn[px] = cnew; hn[px] = og*tanhc(cnew);
  }
  *reinterpret_cast<float4*>(cst + sidx)  = make_float4(cn[0],cn[1],cn[2],cn[3]);
  *reinterpret_cast<float4*>(hnew + sidx) = make_float4(hn[0],hn[1],hn[2],hn[3]);
}

// ---------------------------------------------------------------------------
// 1x1 projections q,kh (hnew), km (m), vh (hnew), vm (m)
// grid (32 ntiles, 4 b), block 256. q/k stored [b][n][16]; v stored [b][n][64]
// ---------------------------------------------------------------------------
__global__ __launch_bounds__(256) void k_proj(
  const float* __restrict__ hnew, const float* __restrict__ mst,
  const float* __restrict__ smalls,
  float* __restrict__ qb, float* __restrict__ khb, float* __restrict__ kmb,
  float* __restrict__ vhb, float* __restrict__ vmb)
{
  __shared__ float hs[64*33];
  __shared__ float ms[64*33];
  int b = blockIdx.y, n0 = blockIdx.x*32;
  int tid = threadIdx.x, nl = tid&31, rg = tid>>5;
  for (int idx = tid; idx < 2048; idx += 256){
    int nn = idx & 31, ch = idx >> 5;
    hs[ch*33+nn] = hnew[((size_t)b*64+ch)*1024 + n0 + nn];
    ms[ch*33+nn] = mst [((size_t)b*64+ch)*1024 + n0 + nn];
  }
  __syncthreads();
  int n = n0 + nl;
  for (int j = 0; j < 22; ++j){
    int r = rg + 8*j;
    const float* src; const float* wrow; float bias; float* dst;
    if (r < 16)      { src = hs; wrow = smalls+O_QW  + r*64;        bias = smalls[O_QB+r];        dst = qb  + ((size_t)b*1024+n)*16 + r; }
    else if (r < 32) { int rr=r-16;  src = hs; wrow = smalls+O_KW  + rr*64; bias = smalls[O_KB+rr];  dst = khb + ((size_t)b*1024+n)*16 + rr; }
    else if (r < 48) { int rr=r-32;  src = ms; wrow = smalls+O_K2W + rr*64; bias = smalls[O_K2B+rr]; dst = kmb + ((size_t)b*1024+n)*16 + rr; }
    else if (r < 112){ int rr=r-48;  src = hs; wrow = smalls+O_VW  + rr*64; bias = smalls[O_VB+rr];  dst = vhb + ((size_t)b*1024+n)*64 + rr; }
    else             { int rr=r-112; src = ms; wrow = smalls+O_V2W + rr*64; bias = smalls[O_V2B+rr]; dst = vmb + ((size_t)b*1024+n)*64 + rr; }
    float acc = bias;
    #pragma unroll
    for (int c4 = 0; c4 < 16; ++c4){
      float4 w4 = *reinterpret_cast<const float4*>(wrow + c4*4);
      acc += w4.x*src[(c4*4+0)*33+nl] + w4.y*src[(c4*4+1)*33+nl]
           + w4.z*src[(c4*4+2)*33+nl] + w4.w*src[(c4*4+3)*33+nl];
    }
    *dst = acc;
  }
}

// ---------------------------------------------------------------------------
// scores + softmax for one branch: att[b][n][m] = softmax_m(sum_a q*k)
// grid (1024 n, 4 b), block 256 (4 m per thread)
// ---------------------------------------------------------------------------
__global__ __launch_bounds__(256) void k_scores(
  const float* __restrict__ qb, const float* __restrict__ kbuf,
  float* __restrict__ att)
{
  int n = blockIdx.x, b = blockIdx.y;
  int tid = threadIdx.x;
  __shared__ float qs[16];
  __shared__ float red[16];
  if (tid < 16) qs[tid] = qb[((size_t)b*1024+n)*16 + tid];
  __syncthreads();
  float qv[16];
  #pragma unroll
  for (int a=0;a<16;++a) qv[a] = qs[a];
  float s[4];
  #pragma unroll
  for (int j=0;j<4;++j){
    int mm = tid + j*256;
    const float4* kp = reinterpret_cast<const float4*>(kbuf + ((size_t)b*1024+mm)*16);
    float a0 = 0.f;
    #pragma unroll
    for (int a4=0;a4<4;++a4){
      float4 kv = kp[a4];
      a0 += qv[a4*4+0]*kv.x + qv[a4*4+1]*kv.y + qv[a4*4+2]*kv.z + qv[a4*4+3]*kv.w;
    }
    s[j] = a0;
  }
  float mx = fmaxf(fmaxf(s[0],s[1]), fmaxf(s[2],s[3]));
  #pragma unroll
  for (int off=32; off>=1; off>>=1) mx = fmaxf(mx, __shfl_xor(mx, off));
  int wv = tid>>6, lane = tid&63;
  if (lane==0) red[wv] = mx;
  __syncthreads();
  mx = fmaxf(fmaxf(red[0],red[1]), fmaxf(red[2],red[3]));
  float e[4]; float sum = 0.f;
  #pragma unroll
  for (int j=0;j<4;++j){ e[j] = __expf(s[j]-mx); sum += e[j]; }
  #pragma unroll
  for (int off=32; off>=1; off>>=1) sum += __shfl_xor(sum, off);
  if (lane==0) red[8+wv] = sum;
  __syncthreads();
  float inv = 1.0f/(red[8]+red[9]+red[10]+red[11]);
  float* arow = att + (((size_t)b)*1024 + n)*1024;
  #pragma unroll
  for (int j=0;j<4;++j) arow[tid + j*256] = e[j]*inv;
}

// ---------------------------------------------------------------------------
// PV for one branch: zcat[b][br*64+c][n] = sum_m att[b][n][m] * v[b][m][c]
// grid (32 ntiles, 4 b), block 256 = 64c x 4ng (8 n each). 64-m chunks.
// ---------------------------------------------------------------------------
__global__ __launch_bounds__(256) void k_pv(
  const float* __restrict__ att, const float* __restrict__ vbuf,
  float* __restrict__ zcat, int br)
{
  __shared__ float att_s[64*40];
  __shared__ float v_s[64*64];
  int n0 = blockIdx.x*32, b = blockIdx.y;
  int tid = threadIdx.x;
  int c = tid & 63, ng = tid >> 6;
  const float* abase = att + (((size_t)b)*1024 + n0)*1024;
  const float* vbase = vbuf + (size_t)b*65536;
  float acc[8] = {0,0,0,0,0,0,0,0};
  for (int mc = 0; mc < 16; ++mc){
    #pragma unroll
    for (int k = 0; k < 8; ++k){
      int idx = tid + k*256;
      int mm = idx & 63, nl = idx >> 6;
      att_s[mm*40 + nl] = abase[(size_t)nl*1024 + mc*64 + mm];
    }
    #pragma unroll
    for (int k = 0; k < 16; ++k){
      int idx = tid + k*256;
      int cc2 = idx & 63, mm = idx >> 6;
      v_s[mm*64 + cc2] = vbase[(mc*64+mm)*64 + cc2];
    }
    __syncthreads();
    for (int mm = 0; mm < 64; ++mm){
      float vv = v_s[mm*64 + c];
      const float4* ap = reinterpret_cast<const float4*>(&att_s[mm*40 + ng*8]);
      float4 a0 = ap[0], a1 = ap[1];
      acc[0] += a0.x*vv; acc[1] += a0.y*vv; acc[2] += a0.z*vv; acc[3] += a0.w*vv;
      acc[4] += a1.x*vv; acc[5] += a1.y*vv; acc[6] += a1.z*vv; acc[7] += a1.w*vv;
    }
    __syncthreads();
  }
  float* tb = att_s;  // reuse as transpose buffer (needs 32*65+... < 2560)
  #pragma unroll
  for (int k = 0; k < 8; ++k){
    int nl = ng*8 + k;
    if (nl < 32) tb[nl*65 + c] = acc[k];
  }
  __syncthreads();
  float* zout = zcat + ((size_t)b*128 + br*64)*1024;
  #pragma unroll
  for (int k = 0; k < 8; ++k){
    int idx = tid + k*256;
    int nl = idx & 31, cc2 = idx >> 5;
    zout[(size_t)cc2*1024 + n0 + nl] = tb[nl*65 + cc2];
  }
}

// ---------------------------------------------------------------------------
// z = z_w@[zh;zm]+z_b; comb = m_w@[z;hnew]+m_b; memory gate; h_out
// grid (32 ntiles, 4 b), block 256. Aliased LDS pool (50.7 KB).
// ---------------------------------------------------------------------------
__global__ __launch_bounds__(256) void k_zcomb(
  const float* __restrict__ zcat, const float* __restrict__ hnew,
  const float* __restrict__ smalls, const int* __restrict__ flagp,
  float* __restrict__ mst, float* __restrict__ hstate,
  void* __restrict__ outraw, int t)
{
  __shared__ float pool[12672];
  float* zt  = pool;          // 128*33 = 4224
  float* hl  = pool + 4224;   // 64*33  = 2112
  float* zin = pool + 6336;   // 128*33 = 4224
  float* cb  = pool + 6336;   // 192*33 = 6336 (aliases zin; used after)
  int n0 = blockIdx.x*32, b = blockIdx.y;
  int tid = threadIdx.x, nl = tid&31, rg = tid>>5;
  int flag = *flagp;
  for (int idx = tid; idx < 4096; idx += 256){
    int nn = idx&31, ch = idx>>5;
    zin[ch*33+nn] = zcat[((size_t)b*128 + ch)*1024 + n0 + nn];
  }
  for (int idx = tid; idx < 2048; idx += 256){
    int nn = idx&31, ch = idx>>5;
    hl[ch*33+nn] = hnew[((size_t)b*64 + ch)*1024 + n0 + nn];
  }
  __syncthreads();
  for (int j = 0; j < 16; ++j){
    int r = rg + 8*j;
    float acc = smalls[O_ZB + r];
    const float* wrow = smalls + O_ZW + r*128;
    #pragma unroll
    for (int c4 = 0; c4 < 32; ++c4){
      float4 w4 = *reinterpret_cast<const float4*>(wrow + c4*4);
      acc += w4.x*zin[(c4*4+0)*33+nl] + w4.y*zin[(c4*4+1)*33+nl]
           + w4.z*zin[(c4*4+2)*33+nl] + w4.w*zin[(c4*4+3)*33+nl];
    }
    zt[r*33+nl] = acc;
  }
  __syncthreads();
  for (int j = 0; j < 24; ++j){
    int r = rg + 8*j;
    float acc = smalls[O_MB + r];
    const float* wrow = smalls + O_MW + r*192;
    #pragma unroll
    for (int c4 = 0; c4 < 32; ++c4){
      float4 w4 = *reinterpret_cast<const float4*>(wrow + c4*4);
      acc += w4.x*zt[(c4*4+0)*33+nl] + w4.y*zt[(c4*4+1)*33+nl]
           + w4.z*zt[(c4*4+2)*33+nl] + w4.w*zt[(c4*4+3)*33+nl];
    }
    #pragma unroll
    for (int c4 = 32; c4 < 48; ++c4){
      float4 w4 = *reinterpret_cast<const float4*>(wrow + c4*4);
      int ch = c4*4 - 128;
      acc += w4.x*hl[(ch+0)*33+nl] + w4.y*hl[(ch+1)*33+nl]
           + w4.z*hl[(ch+2)*33+nl] + w4.w*hl[(ch+3)*33+nl];
    }
    cb[r*33+nl] = acc;
  }
  __syncthreads();
  for (int j = 0; j < 8; ++j){
    int ch = rg + 8*j;
    int n = n0 + nl;
    size_t idx = ((size_t)b*64 + ch)*1024 + n;
    float mo = cb[ch*33+nl], mg = cb[(64+ch)*33+nl], mi = cb[(128+ch)*33+nl];
    float mold = mst[idx];
    float gi = sigm(mi);
    float mnew = (1.0f-gi)*mold + gi*tanhc(mg);
    float ho = sigm(mo)*mnew;
    mst[idx] = mnew;
    hstate[idx] = ho;
    size_t oidx = ((size_t)(b*64+ch)*8 + t)*1024 + n;
    if (flag) ((float*)outraw)[oidx] = ho;
    else      ((bf16*)outraw)[oidx] = __float2bfloat16(ho);
  }
}

extern "C" void kernel_launch(void* const* d_in, const int* in_sizes, int n_in,
                              void* d_out, int out_size, void* d_ws, size_t ws_size,
                              hipStream_t stream)
{
  float* ws = (float*)d_ws;
  int* flag = (int*)(ws + WS_FLAG);
  float* h    = ws + WS_H;
  float* c    = ws + WS_C;
  float* m    = ws + WS_M;
  float* hnew = ws + WS_HNEW;
  float* wre  = ws + WS_WRE;
  float* qb   = ws + WS_QB;
  float* khb  = ws + WS_KHB;
  float* kmb  = ws + WS_KMB;
  float* vhb  = ws + WS_VHB;
  float* vmb  = ws + WS_VMB;
  float* att  = ws + WS_ATT;
  float* zcat = ws + WS_ZCAT;

  k_probe<<<1, 256, 0, stream>>>((const unsigned int*)d_in[0], flag);

  P18 pk;
  for (int i = 0; i < 18; ++i) pk.p[i] = d_in[2 + i];
  k_wconv<<<dim3(256,18), 256, 0, stream>>>(pk, flag, ws);
  k_init<<<3072, 256, 0, stream>>>(d_in[1], flag, ws);

  for (int t = 0; t < 8; ++t){
    k_conv_lstm<<<dim3(8,8,4), 256, 0, stream>>>(flag, d_in[0], wre, ws, h, c, hnew, t);
    k_proj<<<dim3(32,4), 256, 0, stream>>>(hnew, m, ws, qb, khb, kmb, vhb, vmb);
    k_scores<<<dim3(1024,4), 256, 0, stream>>>(qb, khb, att);
    k_pv<<<dim3(32,4), 256, 0, stream>>>(att, vhb, zcat, 0);
    k_scores<<<dim3(1024,4), 256, 0, stream>>>(qb, kmb, att);
    k_pv<<<dim3(32,4), 256, 0, stream>>>(att, vmb, zcat, 1);
    k_zcomb<<<dim3(32,4), 256, 0, stream>>>(zcat, hnew, ws, flag, m, h, d_out, t);
  }
  (void)in_sizes; (void)n_in; (void)out_size; (void)ws_size;
}

// Round 3
// 2277.353 us; speedup vs baseline: 1.3925x; 1.3925x over previous
//
#include <hip/hip_runtime.h>
#include <hip/hip_bf16.h>

typedef __hip_bfloat16 bf16;

__device__ __forceinline__ float b2f(bf16 v){ return __bfloat162float(v); }
__device__ __forceinline__ float sigm(float x){ return 1.0f/(1.0f+__expf(-x)); }
__device__ __forceinline__ float tanhc(float x){
  x = fminf(15.0f, fmaxf(-15.0f, x));
  float e = __expf(2.0f*x);
  return (e-1.0f)/(e+1.0f);
}

// ---------------------------------------------------------------------------
// ws layout (float offsets)
// ---------------------------------------------------------------------------
#define WS_SMALL   0
#define WS_FLAG    262144
#define WS_H       262208
#define WS_C       524352
#define WS_M       786496
#define WS_HNEW    1048640
#define WS_WRE     1310784    // 294912
#define WS_QB      1605696    // 65536
#define WS_KHB     1671232
#define WS_KMB     1736768
#define WS_VHB     1802304    // 262144
#define WS_VMB     2064448
#define WS_ATT0    2326592    // 4194304
#define WS_ATT1    6520896    // 4194304 (only if ws big enough)
#define WS_ZCAT    10715200   // 524288
#define WS_ZWT     11239488   // 16384
#define WS_MWT     11255872   // 36864
#define WS_INVS    11292736   // 8192
#define WS_TOTAL   11300928
// small-weight offsets inside WS_SMALL
#define O_CB    0
#define O_WCI   256
#define O_WCF   65792
#define O_WCO   131328
#define O_QW    196864
#define O_QB    197888
#define O_KW    197904
#define O_KB    198928
#define O_K2W   198944
#define O_K2B   199968
#define O_VW    199984
#define O_VB    204080
#define O_V2W   204144
#define O_V2B   208240
#define O_ZW    208304
#define O_ZB    224688
#define O_MW    224816
#define O_MB    261680

// ---------------------------------------------------------------------------
// dtype probe (f32 vs bf16 input data)
// ---------------------------------------------------------------------------
__global__ void k_probe(const unsigned int* __restrict__ Xu, int* __restrict__ flag){
  __shared__ int cnt;
  if (threadIdx.x == 0) cnt = 0;
  __syncthreads();
  unsigned int u = Xu[threadIdx.x];
  float f = __uint_as_float((u & 0xffffu) << 16);
  int bad = (fabsf(f) <= 1e4f) ? 0 : 1;
  atomicAdd(&cnt, bad);
  __syncthreads();
  if (threadIdx.x == 0) *flag = (cnt > 16) ? 1 : 0;
}

// ---------------------------------------------------------------------------
// convert the 18 small inputs into f32 copies in ws
// ---------------------------------------------------------------------------
struct P18 { const void* p[18]; };

__global__ __launch_bounds__(256) void k_wconv(P18 pk, const int* __restrict__ flagp,
                                               float* __restrict__ dst){
  const int ns[18]   = {256,65536,65536,65536,1024,16,1024,16,1024,16,
                        4096,64,4096,64,16384,128,36864,192};
  const int offs[18] = {O_CB,O_WCI,O_WCF,O_WCO,O_QW,O_QB,O_KW,O_KB,O_K2W,O_K2B,
                        O_VW,O_VB,O_V2W,O_V2B,O_ZW,O_ZB,O_MW,O_MB};
  int y = blockIdx.y;
  int n = ns[y];
  int flag = *flagp;
  const void* src = pk.p[y];
  for (int i = blockIdx.x*256 + threadIdx.x; i < n; i += gridDim.x*256){
    float v = flag ? ((const float*)src)[i] : b2f(((const bf16*)src)[i]);
    dst[offs[y] + i] = v;
  }
}

// transpose z_w (128x128) and m_w (192x192) into [k][r] layout (after k_wconv)
__global__ __launch_bounds__(256) void k_wtrans(float* __restrict__ ws){
  int i = blockIdx.x*256 + threadIdx.x;
  if (i < 16384){
    int k = i >> 7, r = i & 127;
    ws[WS_ZWT + k*128 + r] = ws[O_ZW + r*128 + k];
  }
  if (i < 36864){
    int k = i / 192, r = i - k*192;
    ws[WS_MWT + k*192 + r] = ws[O_MW + r*192 + k];
  }
}

// ---------------------------------------------------------------------------
// init: zero h,c,m and reformat conv weights wre[(o*9+p)*128+ci]
// ---------------------------------------------------------------------------
__global__ __launch_bounds__(256) void k_init(const void* __restrict__ conv_w,
                                              const int* __restrict__ flagp,
                                              float* __restrict__ ws){
  int i = blockIdx.x*256 + threadIdx.x;
  int flag = *flagp;
  if (i < 786432) ws[WS_H + i] = 0.0f;
  if (i < 294912){
    int ci = i & 127;
    int rest = i >> 7;
    int p = rest % 9;
    int o = rest / 9;
    int si = (o*128 + ci)*9 + p;
    ws[WS_WRE + i] = flag ? ((const float*)conv_w)[si] : b2f(((const bf16*)conv_w)[si]);
  }
}

// ---------------------------------------------------------------------------
// conv 3x3 (128 -> 256ch) + peephole LSTM pointwise. Two 64-ci phases.
// grid (8 cg, 16 yg, 4 b) = 512 blocks; block 256 = 8cc x 2yl x 16xt (2px)
// LDS: 4 rows x 64ci x 36 f32 = 36.9 KB
// ---------------------------------------------------------------------------
#define CRW 2304
__global__ __launch_bounds__(256) void k_conv_lstm(
  const int* __restrict__ flagp, const void* __restrict__ Xraw,
  const float* __restrict__ wre, const float* __restrict__ smalls,
  const float* __restrict__ hprev, float* __restrict__ cst,
  float* __restrict__ hnew, int t)
{
  __shared__ float lds[4*CRW];
  int cg = blockIdx.x, yg = blockIdx.y, b = blockIdx.z;
  int tid = threadIdx.x;
  int flag = *flagp;
  int xt = tid & 15, yl = (tid>>4)&1, cl = tid>>5;
  int cc = cg*8 + cl;

  float acc[4][2];
  #pragma unroll
  for (int g=0; g<4; ++g){
    float bv = smalls[O_CB + g*64 + cc];
    acc[g][0]=bv; acc[g][1]=bv;
  }

  for (int ph = 0; ph < 2; ++ph){
    if (ph) __syncthreads();
    for (int idx = tid; idx < 4*64*34; idx += 256){
      int row = idx / 2176;
      int rem = idx - row*2176;
      int ci  = rem / 34;
      int xp  = rem - ci*34;
      int yin = yg*2 - 1 + row;
      int xin = xp - 1;
      float v = 0.0f;
      if (yin >= 0 && yin < 32 && xin >= 0 && xin < 32){
        if (ph == 0){
          int si = (((b*64+ci)*8 + t)*32 + yin)*32 + xin;
          v = flag ? ((const float*)Xraw)[si] : b2f(((const bf16*)Xraw)[si]);
        } else {
          v = hprev[((b*64 + ci)*32 + yin)*32 + xin];
        }
      }
      lds[row*CRW + ci*36 + xp] = v;
    }
    __syncthreads();

    const float* wbase = wre + (size_t)cc*1152 + ph*64;
    for (int dy=0; dy<3; ++dy){
      const float* lrow = lds + (yl+dy)*CRW;
      for (int ci4=0; ci4<16; ++ci4){
        float iv[4][4];
        #pragma unroll
        for (int j=0;j<4;++j){
          const float* lp = lrow + (ci4*4+j)*36 + xt*2;
          float2 a0 = *reinterpret_cast<const float2*>(lp);
          float2 a1 = *reinterpret_cast<const float2*>(lp+2);
          iv[j][0]=a0.x; iv[j][1]=a0.y; iv[j][2]=a1.x; iv[j][3]=a1.y;
        }
        #pragma unroll
        for (int dx=0; dx<3; ++dx){
          int p = dy*3+dx;
          #pragma unroll
          for (int g=0; g<4; ++g){
            const float4 w4 = *reinterpret_cast<const float4*>(wbase + (size_t)g*73728 + p*128 + ci4*4);
            #pragma unroll
            for (int px=0;px<2;++px){
              acc[g][px] += w4.x*iv[0][px+dx] + w4.y*iv[1][px+dx]
                          + w4.z*iv[2][px+dx] + w4.w*iv[3][px+dx];
            }
          }
        }
      }
    }
  }

  int y = yg*2 + yl, x0 = xt*2;
  int nbase = y*32 + x0;
  size_t sidx = ((size_t)(b*64+cc))*1024 + nbase;
  float2 c2 = *reinterpret_cast<const float2*>(cst + sidx);
  float cn[2], hn[2];
  #pragma unroll
  for (int px=0; px<2; ++px){
    float cprev = (&c2.x)[px];
    int wi = cc*1024 + nbase + px;
    float ig = sigm(acc[0][px] + smalls[O_WCI + wi]*cprev);
    float fg = sigm(acc[1][px] + smalls[O_WCF + wi]*cprev);
    float cnew = fg*cprev + ig*tanhc(acc[2][px]);
    float og = sigm(acc[3][px] + smalls[O_WCO + wi]*cnew);
    cn[px] = cnew; hn[px] = og*tanhc(cnew);
  }
  *reinterpret_cast<float2*>(cst + sidx)  = make_float2(cn[0],cn[1]);
  *reinterpret_cast<float2*>(hnew + sidx) = make_float2(hn[0],hn[1]);
}

// ---------------------------------------------------------------------------
// 1x1 projections q,kh (hnew), km (m), vh (hnew), vm (m)
// grid (64 ntiles of 16, 4 b) = 256 blocks, block 256
// ---------------------------------------------------------------------------
__global__ __launch_bounds__(256) void k_proj(
  const float* __restrict__ hnew, const float* __restrict__ mst,
  const float* __restrict__ smalls,
  float* __restrict__ qb, float* __restrict__ khb, float* __restrict__ kmb,
  float* __restrict__ vhb, float* __restrict__ vmb)
{
  __shared__ float hs[64*17];
  __shared__ float ms[64*17];
  int b = blockIdx.y, n0 = blockIdx.x*16;
  int tid = threadIdx.x, nl = tid&15, rg = tid>>4;
  for (int idx = tid; idx < 1024; idx += 256){
    int nn = idx & 15, ch = idx >> 4;
    hs[ch*17+nn] = hnew[((size_t)b*64+ch)*1024 + n0 + nn];
    ms[ch*17+nn] = mst [((size_t)b*64+ch)*1024 + n0 + nn];
  }
  __syncthreads();
  int n = n0 + nl;
  for (int j = 0; j < 11; ++j){
    int r = rg + 16*j;
    const float* src; const float* wrow; float bias; float* dst;
    if (r < 16)      { src = hs; wrow = smalls+O_QW  + r*64;        bias = smalls[O_QB+r];        dst = qb  + ((size_t)b*1024+n)*16 + r; }
    else if (r < 32) { int rr=r-16;  src = hs; wrow = smalls+O_KW  + rr*64; bias = smalls[O_KB+rr];  dst = khb + ((size_t)b*1024+n)*16 + rr; }
    else if (r < 48) { int rr=r-32;  src = ms; wrow = smalls+O_K2W + rr*64; bias = smalls[O_K2B+rr]; dst = kmb + ((size_t)b*1024+n)*16 + rr; }
    else if (r < 112){ int rr=r-48;  src = hs; wrow = smalls+O_VW  + rr*64; bias = smalls[O_VB+rr];  dst = vhb + ((size_t)b*1024+n)*64 + rr; }
    else             { int rr=r-112; src = ms; wrow = smalls+O_V2W + rr*64; bias = smalls[O_V2B+rr]; dst = vmb + ((size_t)b*1024+n)*64 + rr; }
    float acc = bias;
    #pragma unroll
    for (int c4 = 0; c4 < 16; ++c4){
      float4 w4 = *reinterpret_cast<const float4*>(wrow + c4*4);
      acc += w4.x*src[(c4*4+0)*17+nl] + w4.y*src[(c4*4+1)*17+nl]
           + w4.z*src[(c4*4+2)*17+nl] + w4.w*src[(c4*4+3)*17+nl];
    }
    *dst = acc;
  }
}

// ---------------------------------------------------------------------------
// scores: att[br][b][n][m] = exp(qk) (UNNORMALIZED), invs[br][b][n] = 1/rowsum
// grid (32 ntiles of 32, 4 b, nbr), block 256: thread n = n0+(tid>>3), mg=tid&7
// ---------------------------------------------------------------------------
__global__ __launch_bounds__(256) void k_scores(
  const float* __restrict__ qb, const float* __restrict__ khb, const float* __restrict__ kmb,
  float* __restrict__ att0, float* __restrict__ att1, float* __restrict__ invs, int brbase)
{
  __shared__ float q_s[32*20];
  __shared__ float k_s[256*24];
  int n0 = blockIdx.x*32, b = blockIdx.y, br = blockIdx.z + brbase;
  const float* kbuf = br ? kmb : khb;
  float* att = br ? att1 : att0;
  int tid = threadIdx.x;
  int nl = tid>>3, mg = tid&7;
  int n = n0 + nl;
  for (int idx = tid; idx < 512; idx += 256){
    int nn = idx >> 4, a = idx & 15;
    q_s[nn*20 + a] = qb[((size_t)b*1024 + n0 + nn)*16 + a];
  }
  __syncthreads();
  float ql[16];
  #pragma unroll
  for (int a4 = 0; a4 < 4; ++a4){
    float4 v = *reinterpret_cast<const float4*>(&q_s[nl*20 + a4*4]);
    ql[a4*4+0]=v.x; ql[a4*4+1]=v.y; ql[a4*4+2]=v.z; ql[a4*4+3]=v.w;
  }
  float rsum = 0.0f;
  for (int mc = 0; mc < 4; ++mc){
    __syncthreads();
    for (int idx = tid; idx < 4096; idx += 256){
      int mm = idx >> 4, a = idx & 15;
      k_s[mm*24 + a] = kbuf[((size_t)b*1024 + mc*256 + mm)*16 + a];
    }
    __syncthreads();
    float* arow = att + ((size_t)b*1024 + n)*1024 + mc*256;
    #pragma unroll 4
    for (int kk = 0; kk < 32; ++kk){
      int mm = mg + kk*8;
      float s = 0.0f;
      #pragma unroll
      for (int a4 = 0; a4 < 4; ++a4){
        float4 kv = *reinterpret_cast<const float4*>(&k_s[mm*24 + a4*4]);
        s += ql[a4*4+0]*kv.x + ql[a4*4+1]*kv.y + ql[a4*4+2]*kv.z + ql[a4*4+3]*kv.w;
      }
      float e = __expf(fminf(s, 60.0f));
      rsum += e;
      arow[mm] = e;
    }
  }
  rsum += __shfl_xor(rsum, 1);
  rsum += __shfl_xor(rsum, 2);
  rsum += __shfl_xor(rsum, 4);
  if (mg == 0) invs[((size_t)(br*4+b))*1024 + n] = 1.0f/rsum;
}

// ---------------------------------------------------------------------------
// PV: zcat[b][br*64+c][n0..] = invs[n] * sum_m att[br][b][n][m] * v[b][m][c]
// grid (32 ntiles of 32, 4 b, nbr), block 256 = 2 K-halves x (16cq x 8nq)
// 16 accs/thread (4n x 4c). 8 chunks of 128 m, each half does 64 m.
// ---------------------------------------------------------------------------
__global__ __launch_bounds__(256) void k_pv(
  const float* __restrict__ att0, const float* __restrict__ att1,
  const float* __restrict__ vhb, const float* __restrict__ vmb,
  const float* __restrict__ invs, float* __restrict__ zcat, int brbase)
{
  __shared__ float att_s[128*36];   // [mm][n] pad 36
  __shared__ float v_s[128*68];     // [mm][c] pad 68
  int n0 = blockIdx.x*32, b = blockIdx.y, br = blockIdx.z + brbase;
  const float* att = br ? att1 : att0;
  const float* vbuf = br ? vmb : vhb;
  int tid = threadIdx.x;
  int half = tid >> 7, idh = tid & 127;
  int cq = idh & 15, nq = idh >> 4;     // c = cq*4, n = nq*4
  float acc[4][4];
  #pragma unroll
  for (int i=0;i<4;++i){ acc[i][0]=0.f; acc[i][1]=0.f; acc[i][2]=0.f; acc[i][3]=0.f; }
  const float* abase = att + ((size_t)b*1024 + n0)*1024;
  const float* vbase = vbuf + (size_t)b*65536;
  for (int mc = 0; mc < 8; ++mc){
    #pragma unroll
    for (int k = 0; k < 16; ++k){
      int idx = tid + k*256;
      int mm = idx & 127, nn = idx >> 7;
      att_s[mm*36 + nn] = abase[(size_t)nn*1024 + mc*128 + mm];
    }
    #pragma unroll
    for (int k = 0; k < 32; ++k){
      int idx = tid + k*256;
      int c = idx & 63, mm = idx >> 6;
      v_s[mm*68 + c] = vbase[(size_t)(mc*128+mm)*64 + c];
    }
    __syncthreads();
    #pragma unroll 2
    for (int mm0 = 0; mm0 < 64; ++mm0){
      int mm = half*64 + mm0;
      float4 p4 = *reinterpret_cast<const float4*>(&att_s[mm*36 + nq*4]);
      float4 v4 = *reinterpret_cast<const float4*>(&v_s[mm*68 + cq*4]);
      #pragma unroll
      for (int i=0;i<4;++i){
        float p = (&p4.x)[i];
        acc[i][0] += p*v4.x; acc[i][1] += p*v4.y; acc[i][2] += p*v4.z; acc[i][3] += p*v4.w;
      }
    }
    __syncthreads();
  }
  // cross-half reduction: half1 writes to LDS (reuse att_s), half0 adds
  float* red = att_s;  // [32n][68c]
  if (half == 1){
    #pragma unroll
    for (int i=0;i<4;++i)
      *reinterpret_cast<float4*>(&red[(nq*4+i)*68 + cq*4]) = make_float4(acc[i][0],acc[i][1],acc[i][2],acc[i][3]);
  }
  __syncthreads();
  float* tb = v_s;     // [64c][36n]
  if (half == 0){
    float inv[4];
    #pragma unroll
    for (int i=0;i<4;++i) inv[i] = invs[((size_t)(br*4+b))*1024 + n0 + nq*4 + i];
    #pragma unroll
    for (int i=0;i<4;++i){
      float4 r4 = *reinterpret_cast<const float4*>(&red[(nq*4+i)*68 + cq*4]);
      #pragma unroll
      for (int j=0;j<4;++j){
        float o = (acc[i][j] + (&r4.x)[j]) * inv[i];
        tb[(cq*4+j)*36 + nq*4+i] = o;
      }
    }
  }
  __syncthreads();
  float* zout = zcat + ((size_t)b*128 + br*64)*1024;
  for (int idx = tid; idx < 2048; idx += 256){
    int nn = idx & 31, ch = idx >> 5;
    zout[(size_t)ch*1024 + n0 + nn] = tb[ch*36 + nn];
  }
}

// ---------------------------------------------------------------------------
// zcomb: zt = zwT^T@zcat+z_b; comb = mwT^T@[zt;hnew]+m_b; gate; h_out
// grid (128 tiles of 8px, 4 b) = 512 blocks; block 256 = 8px x 32lr
// ---------------------------------------------------------------------------
__global__ __launch_bounds__(256) void k_zcomb(
  const float* __restrict__ zcat, const float* __restrict__ hnew,
  const float* __restrict__ smalls, const float* __restrict__ zwT,
  const float* __restrict__ mwT, const int* __restrict__ flagp,
  float* __restrict__ mst, float* __restrict__ hstate,
  void* __restrict__ outraw, int t)
{
  __shared__ float zin[128*9];
  __shared__ float hl [64*9];
  __shared__ float ml [64*9];
  __shared__ float zt_s[8*132];
  __shared__ float ho_s[128*9];
  __shared__ float mn_s[64*9];
  int n0 = blockIdx.x*8, b = blockIdx.y;
  int tid = threadIdx.x;
  int px = tid >> 5, lr = tid & 31;
  int flag = *flagp;
  for (int idx = tid; idx < 1024; idx += 256){
    int ch = idx >> 3, pp = idx & 7;
    zin[ch*9+pp] = zcat[((size_t)b*128 + ch)*1024 + n0 + pp];
  }
  for (int idx = tid; idx < 512; idx += 256){
    int ch = idx >> 3, pp = idx & 7;
    hl[ch*9+pp] = hnew[((size_t)b*64 + ch)*1024 + n0 + pp];
    ml[ch*9+pp] = mst [((size_t)b*64 + ch)*1024 + n0 + pp];
  }
  __syncthreads();
  // phase 1: zt rows r = lr*4..lr*4+3
  {
    float4 a4 = *reinterpret_cast<const float4*>(&smalls[O_ZB + lr*4]);
    float acc0=a4.x, acc1=a4.y, acc2=a4.z, acc3=a4.w;
    #pragma unroll 4
    for (int k = 0; k < 128; ++k){
      float zv = zin[k*9 + px];
      float4 w4 = *reinterpret_cast<const float4*>(&zwT[k*128 + lr*4]);
      acc0 += w4.x*zv; acc1 += w4.y*zv; acc2 += w4.z*zv; acc3 += w4.w*zv;
    }
    *reinterpret_cast<float4*>(&zt_s[px*132 + lr*4]) = make_float4(acc0,acc1,acc2,acc3);
  }
  __syncthreads();
  // phase 2: comb rows r = lr + 32i, i=0..5
  {
    float acc[6];
    #pragma unroll
    for (int i=0;i<6;++i) acc[i] = smalls[O_MB + lr + 32*i];
    const float* ztrow = &zt_s[px*132];
    #pragma unroll 2
    for (int k = 0; k < 128; ++k){
      float xv = ztrow[k];
      const float* wr = &mwT[k*192 + lr];
      #pragma unroll
      for (int i=0;i<6;++i) acc[i] += wr[32*i]*xv;
    }
    #pragma unroll 2
    for (int k = 0; k < 64; ++k){
      float xv = hl[k*9 + px];
      const float* wr = &mwT[(128+k)*192 + lr];
      #pragma unroll
      for (int i=0;i<6;++i) acc[i] += wr[32*i]*xv;
    }
    // rows: i=0,1 -> mo(ch=lr,lr+32); i=2,3 -> mg; i=4,5 -> mi
    #pragma unroll
    for (int j=0;j<2;++j){
      int ch = lr + 32*j;
      float mold = ml[ch*9 + px];
      float gi = sigm(acc[4+j]);
      float mnew = (1.0f-gi)*mold + gi*tanhc(acc[2+j]);
      float ho = sigm(acc[j])*mnew;
      ho_s[ch*9+px] = ho;
      mn_s[ch < 64 ? ch*9+px : 0] = 0.0f; // placeholder avoid branch issues
      mn_s[ch*9+px >= 576 ? 0 : ch*9+px] = mnew;
    }
  }
  __syncthreads();
  for (int idx = tid; idx < 512; idx += 256){
    int ch = idx >> 3, pp = idx & 7;
    int n = n0 + pp;
    size_t gidx = ((size_t)b*64 + ch)*1024 + n;
    mst[gidx] = mn_s[ch*9+pp];
  }
  for (int idx = tid; idx < 512; idx += 256){
    int ch = idx >> 3, pp = idx & 7;
    int n = n0 + pp;
    size_t gidx = ((size_t)b*64 + ch)*1024 + n;
    float ho = ho_s[ch*9+pp];
    hstate[gidx] = ho;
    size_t oidx = ((size_t)(b*64+ch)*8 + t)*1024 + n;
    if (flag) ((float*)outraw)[oidx] = ho;
    else      ((bf16*)outraw)[oidx] = __float2bfloat16(ho);
  }
}

extern "C" void kernel_launch(void* const* d_in, const int* in_sizes, int n_in,
                              void* d_out, int out_size, void* d_ws, size_t ws_size,
                              hipStream_t stream)
{
  float* ws = (float*)d_ws;
  int* flag = (int*)(ws + WS_FLAG);
  float* h    = ws + WS_H;
  float* c    = ws + WS_C;
  float* m    = ws + WS_M;
  float* hnew = ws + WS_HNEW;
  float* wre  = ws + WS_WRE;
  float* qb   = ws + WS_QB;
  float* khb  = ws + WS_KHB;
  float* kmb  = ws + WS_KMB;
  float* vhb  = ws + WS_VHB;
  float* vmb  = ws + WS_VMB;
  float* att0 = ws + WS_ATT0;
  float* zcat = ws + WS_ZCAT;
  float* zwT  = ws + WS_ZWT;
  float* mwT  = ws + WS_MWT;
  float* invs = ws + WS_INVS;
  bool bigws = ws_size >= (size_t)WS_TOTAL * sizeof(float);
  float* att1 = bigws ? (ws + WS_ATT1) : att0;

  k_probe<<<1, 256, 0, stream>>>((const unsigned int*)d_in[0], flag);
  P18 pk;
  for (int i = 0; i < 18; ++i) pk.p[i] = d_in[2 + i];
  k_wconv<<<dim3(64,18), 256, 0, stream>>>(pk, flag, ws);
  k_init<<<3072, 256, 0, stream>>>(d_in[1], flag, ws);
  k_wtrans<<<208, 256, 0, stream>>>(ws);

  for (int t = 0; t < 8; ++t){
    k_conv_lstm<<<dim3(8,16,4), 256, 0, stream>>>(flag, d_in[0], wre, ws, h, c, hnew, t);
    k_proj<<<dim3(64,4), 256, 0, stream>>>(hnew, m, ws, qb, khb, kmb, vhb, vmb);
    if (bigws){
      k_scores<<<dim3(32,4,2), 256, 0, stream>>>(qb, khb, kmb, att0, att1, invs, 0);
      k_pv<<<dim3(32,4,2), 256, 0, stream>>>(att0, att1, vhb, vmb, invs, zcat, 0);
    } else {
      k_scores<<<dim3(32,4,1), 256, 0, stream>>>(qb, khb, kmb, att0, att1, invs, 0);
      k_pv<<<dim3(32,4,1), 256, 0, stream>>>(att0, att1, vhb, vmb, invs, zcat, 0);
      k_scores<<<dim3(32,4,1), 256, 0, stream>>>(qb, khb, kmb, att0, att1, invs, 1);
      k_pv<<<dim3(32,4,1), 256, 0, stream>>>(att0, att1, vhb, vmb, invs, zcat, 1);
    }
    k_zcomb<<<dim3(128,4), 256, 0, stream>>>(zcat, hnew, ws, zwT, mwT, flag, m, h, d_out, t);
  }
  (void)in_sizes; (void)n_in; (void)out_size;
}

// Round 4
// 1511.330 us; speedup vs baseline: 2.0982x; 1.5069x over previous
//
#include <hip/hip_runtime.h>
#include <hip/hip_bf16.h>

typedef __hip_bfloat16 bf16;

__device__ __forceinline__ float b2f(bf16 v){ return __bfloat162float(v); }
__device__ __forceinline__ float sigm(float x){ return 1.0f/(1.0f+__expf(-x)); }
__device__ __forceinline__ float tanhc(float x){
  x = fminf(15.0f, fmaxf(-15.0f, x));
  float e = __expf(2.0f*x);
  return (e-1.0f)/(e+1.0f);
}

// ---------------------------------------------------------------------------
// ws layout (float offsets)
// ---------------------------------------------------------------------------
#define WS_SMALL   0          // 262144
#define WS_FLAG    262144     // 64
#define WS_H       262208
#define WS_C       524352
#define WS_M       786496
#define WS_HNEW    1048640
#define WS_WRE     1310784    // 294912
#define WS_QB      1605696    // 65536
#define WS_KHB     1671232    // 65536
#define WS_KMB     1736768    // 65536
#define WS_VHB     1802304    // 262144
#define WS_VMB     2064448    // 262144
#define WS_ZCAT    2326592    // 524288
#define WS_ZWT     2850880    // 16384
#define WS_MW4     2867264    // 36864  (total 2904128 f = 11.6 MB)
// small-weight offsets inside WS_SMALL
#define O_CB    0
#define O_WCI   256
#define O_WCF   65792
#define O_WCO   131328
#define O_QW    196864
#define O_QB    197888
#define O_KW    197904
#define O_KB    198928
#define O_K2W   198944
#define O_K2B   199968
#define O_VW    199984
#define O_VB    204080
#define O_V2W   204144
#define O_V2B   208240
#define O_ZW    208304
#define O_ZB    224688
#define O_MW    224816
#define O_MB    261680

// ---------------------------------------------------------------------------
// dtype probe (f32 vs bf16 input data)
// ---------------------------------------------------------------------------
__global__ void k_probe(const unsigned int* __restrict__ Xu, int* __restrict__ flag){
  __shared__ int cnt;
  if (threadIdx.x == 0) cnt = 0;
  __syncthreads();
  unsigned int u = Xu[threadIdx.x];
  float f = __uint_as_float((u & 0xffffu) << 16);
  int bad = (fabsf(f) <= 1e4f) ? 0 : 1;
  atomicAdd(&cnt, bad);
  __syncthreads();
  if (threadIdx.x == 0) *flag = (cnt > 16) ? 1 : 0;
}

// ---------------------------------------------------------------------------
// convert the 18 small inputs into f32 copies in ws
// ---------------------------------------------------------------------------
struct P18 { const void* p[18]; };

__global__ __launch_bounds__(256) void k_wconv(P18 pk, const int* __restrict__ flagp,
                                               float* __restrict__ dst){
  const int ns[18]   = {256,65536,65536,65536,1024,16,1024,16,1024,16,
                        4096,64,4096,64,16384,128,36864,192};
  const int offs[18] = {O_CB,O_WCI,O_WCF,O_WCO,O_QW,O_QB,O_KW,O_KB,O_K2W,O_K2B,
                        O_VW,O_VB,O_V2W,O_V2B,O_ZW,O_ZB,O_MW,O_MB};
  int y = blockIdx.y;
  int n = ns[y];
  int flag = *flagp;
  const void* src = pk.p[y];
  for (int i = blockIdx.x*256 + threadIdx.x; i < n; i += gridDim.x*256){
    float v = flag ? ((const float*)src)[i] : b2f(((const bf16*)src)[i]);
    dst[offs[y] + i] = v;
  }
}

// transpose z_w into [k][r]; pack m_w into mw4[(k4*192 + r)*4 + q] = m_w[r][k4*4+q]
__global__ __launch_bounds__(256) void k_wtrans(float* __restrict__ ws){
  int i = blockIdx.x*256 + threadIdx.x;
  if (i < 16384){
    int k = i >> 7, r = i & 127;
    ws[WS_ZWT + k*128 + r] = ws[O_ZW + r*128 + k];
  }
  if (i < 36864){
    int q = i & 3; int rest = i >> 2; int r = rest % 192; int k4 = rest / 192;
    ws[WS_MW4 + i] = ws[O_MW + r*192 + k4*4 + q];
  }
}

// ---------------------------------------------------------------------------
// init: zero h,c,m and reformat conv weights wre[(o*9+p)*128+ci]
// ---------------------------------------------------------------------------
__global__ __launch_bounds__(256) void k_init(const void* __restrict__ conv_w,
                                              const int* __restrict__ flagp,
                                              float* __restrict__ ws){
  int i = blockIdx.x*256 + threadIdx.x;
  int flag = *flagp;
  if (i < 786432) ws[WS_H + i] = 0.0f;
  if (i < 294912){
    int ci = i & 127;
    int rest = i >> 7;
    int p = rest % 9;
    int o = rest / 9;
    int si = (o*128 + ci)*9 + p;
    ws[WS_WRE + i] = flag ? ((const float*)conv_w)[si] : b2f(((const bf16*)conv_w)[si]);
  }
}

// ---------------------------------------------------------------------------
// conv 3x3 (128 -> 256ch) + peephole LSTM pointwise. Two 64-ci phases.
// grid (8 cg, 16 yg, 4 b) = 512 blocks; block 256 = 8cc x 2yl x 16xt (2px)
// ---------------------------------------------------------------------------
#define CRW 2304
__global__ __launch_bounds__(256) void k_conv_lstm(
  const int* __restrict__ flagp, const void* __restrict__ Xraw,
  const float* __restrict__ wre, const float* __restrict__ smalls,
  const float* __restrict__ hprev, float* __restrict__ cst,
  float* __restrict__ hnew, int t)
{
  __shared__ float lds[4*CRW];
  int cg = blockIdx.x, yg = blockIdx.y, b = blockIdx.z;
  int tid = threadIdx.x;
  int flag = *flagp;
  int xt = tid & 15, yl = (tid>>4)&1, cl = tid>>5;
  int cc = cg*8 + cl;

  float acc[4][2];
  #pragma unroll
  for (int g=0; g<4; ++g){
    float bv = smalls[O_CB + g*64 + cc];
    acc[g][0]=bv; acc[g][1]=bv;
  }

  for (int ph = 0; ph < 2; ++ph){
    if (ph) __syncthreads();
    for (int idx = tid; idx < 4*64*34; idx += 256){
      int row = idx / 2176;
      int rem = idx - row*2176;
      int ci  = rem / 34;
      int xp  = rem - ci*34;
      int yin = yg*2 - 1 + row;
      int xin = xp - 1;
      float v = 0.0f;
      if (yin >= 0 && yin < 32 && xin >= 0 && xin < 32){
        if (ph == 0){
          int si = (((b*64+ci)*8 + t)*32 + yin)*32 + xin;
          v = flag ? ((const float*)Xraw)[si] : b2f(((const bf16*)Xraw)[si]);
        } else {
          v = hprev[((b*64 + ci)*32 + yin)*32 + xin];
        }
      }
      lds[row*CRW + ci*36 + xp] = v;
    }
    __syncthreads();

    const float* wbase = wre + (size_t)cc*1152 + ph*64;
    for (int dy=0; dy<3; ++dy){
      const float* lrow = lds + (yl+dy)*CRW;
      for (int ci4=0; ci4<16; ++ci4){
        float iv[4][4];
        #pragma unroll
        for (int j=0;j<4;++j){
          const float* lp = lrow + (ci4*4+j)*36 + xt*2;
          float2 a0 = *reinterpret_cast<const float2*>(lp);
          float2 a1 = *reinterpret_cast<const float2*>(lp+2);
          iv[j][0]=a0.x; iv[j][1]=a0.y; iv[j][2]=a1.x; iv[j][3]=a1.y;
        }
        #pragma unroll
        for (int dx=0; dx<3; ++dx){
          int p = dy*3+dx;
          #pragma unroll
          for (int g=0; g<4; ++g){
            const float4 w4 = *reinterpret_cast<const float4*>(wbase + (size_t)g*73728 + p*128 + ci4*4);
            #pragma unroll
            for (int px=0;px<2;++px){
              acc[g][px] += w4.x*iv[0][px+dx] + w4.y*iv[1][px+dx]
                          + w4.z*iv[2][px+dx] + w4.w*iv[3][px+dx];
            }
          }
        }
      }
    }
  }

  int y = yg*2 + yl, x0 = xt*2;
  int nbase = y*32 + x0;
  size_t sidx = ((size_t)(b*64+cc))*1024 + nbase;
  float2 c2 = *reinterpret_cast<const float2*>(cst + sidx);
  float cn[2], hn[2];
  #pragma unroll
  for (int px=0; px<2; ++px){
    float cprev = (&c2.x)[px];
    int wi = cc*1024 + nbase + px;
    float ig = sigm(acc[0][px] + smalls[O_WCI + wi]*cprev);
    float fg = sigm(acc[1][px] + smalls[O_WCF + wi]*cprev);
    float cnew = fg*cprev + ig*tanhc(acc[2][px]);
    float og = sigm(acc[3][px] + smalls[O_WCO + wi]*cnew);
    cn[px] = cnew; hn[px] = og*tanhc(cnew);
  }
  *reinterpret_cast<float2*>(cst + sidx)  = make_float2(cn[0],cn[1]);
  *reinterpret_cast<float2*>(hnew + sidx) = make_float2(hn[0],hn[1]);
}

// ---------------------------------------------------------------------------
// 1x1 projections q,kh (hnew), km (m), vh (hnew), vm (m)
// grid (64 ntiles of 16, 4 b) = 256 blocks, block 256
// ---------------------------------------------------------------------------
__global__ __launch_bounds__(256) void k_proj(
  const float* __restrict__ hnew, const float* __restrict__ mst,
  const float* __restrict__ smalls,
  float* __restrict__ qb, float* __restrict__ khb, float* __restrict__ kmb,
  float* __restrict__ vhb, float* __restrict__ vmb)
{
  __shared__ float hs[64*17];
  __shared__ float ms[64*17];
  int b = blockIdx.y, n0 = blockIdx.x*16;
  int tid = threadIdx.x, nl = tid&15, rg = tid>>4;
  for (int idx = tid; idx < 1024; idx += 256){
    int nn = idx & 15, ch = idx >> 4;
    hs[ch*17+nn] = hnew[((size_t)b*64+ch)*1024 + n0 + nn];
    ms[ch*17+nn] = mst [((size_t)b*64+ch)*1024 + n0 + nn];
  }
  __syncthreads();
  int n = n0 + nl;
  for (int j = 0; j < 11; ++j){
    int r = rg + 16*j;
    const float* src; const float* wrow; float bias; float* dst;
    if (r < 16)      { src = hs; wrow = smalls+O_QW  + r*64;        bias = smalls[O_QB+r];        dst = qb  + ((size_t)b*1024+n)*16 + r; }
    else if (r < 32) { int rr=r-16;  src = hs; wrow = smalls+O_KW  + rr*64; bias = smalls[O_KB+rr];  dst = khb + ((size_t)b*1024+n)*16 + rr; }
    else if (r < 48) { int rr=r-32;  src = ms; wrow = smalls+O_K2W + rr*64; bias = smalls[O_K2B+rr]; dst = kmb + ((size_t)b*1024+n)*16 + rr; }
    else if (r < 112){ int rr=r-48;  src = hs; wrow = smalls+O_VW  + rr*64; bias = smalls[O_VB+rr];  dst = vhb + ((size_t)b*1024+n)*64 + rr; }
    else             { int rr=r-112; src = ms; wrow = smalls+O_V2W + rr*64; bias = smalls[O_V2B+rr]; dst = vmb + ((size_t)b*1024+n)*64 + rr; }
    float acc = bias;
    #pragma unroll
    for (int c4 = 0; c4 < 16; ++c4){
      float4 w4 = *reinterpret_cast<const float4*>(wrow + c4*4);
      acc += w4.x*src[(c4*4+0)*17+nl] + w4.y*src[(c4*4+1)*17+nl]
           + w4.z*src[(c4*4+2)*17+nl] + w4.w*src[(c4*4+3)*17+nl];
    }
    *dst = acc;
  }
}

// ---------------------------------------------------------------------------
// fused flash attention (both branches, unnormalized exp + final 1/rowsum):
// zcat[b][br*64+c][n] = (1/rsum[n]) * sum_m exp(q[n]·k[m]) v[m][c]
// grid (32 ntiles of 32, 4 b, 2 br), block 512 = 8 waves.
// score role: wave sng owns n = sng*4..+3; lane smg owns m = smg, smg+64.
// pv role: wave pg owns m-slice [pg*16,pg*16+16); thread = (pnq:4n, pcq:8c).
// epilogue: full-wave shfl rsum, 3-round LDS tree over 8 wave-partials.
// ---------------------------------------------------------------------------
__global__ __launch_bounds__(512) void k_fatt(
  const float* __restrict__ qb, const float* __restrict__ khb, const float* __restrict__ kmb,
  const float* __restrict__ vhb, const float* __restrict__ vmb,
  float* __restrict__ zcat)
{
  __shared__ float k_s[128*20];   // [m][a]
  __shared__ float v_s[128*64];   // [m][c]; reused as reduction buffer
  __shared__ float e_s[128*36];   // [m][n]; reused as transpose-out buffer
  __shared__ float q_s[32*20];
  __shared__ float rinv_s[32];
  int n0 = blockIdx.x*32, b = blockIdx.y, br = blockIdx.z;
  const float* kbuf = br ? kmb : khb;
  const float* vbuf = br ? vmb : vhb;
  int tid = threadIdx.x;
  int sng = tid >> 6;        // wave id (score role: 4 n's)
  int smg = tid & 63;
  int pg  = sng;             // wave id (pv role: 16-m slice)
  int pnq = (tid >> 3) & 7;  // 4 n's
  int pcq = tid & 7;         // 8 c's

  {
    int nn = tid >> 4, a = tid & 15;
    q_s[nn*20 + a] = qb[((size_t)b*1024 + n0 + nn)*16 + a];
  }
  __syncthreads();
  float qreg[4][16];
  #pragma unroll
  for (int i=0;i<4;++i){
    #pragma unroll
    for (int a4=0;a4<4;++a4){
      float4 v = *reinterpret_cast<const float4*>(&q_s[(sng*4+i)*20 + a4*4]);
      qreg[i][a4*4+0]=v.x; qreg[i][a4*4+1]=v.y; qreg[i][a4*4+2]=v.z; qreg[i][a4*4+3]=v.w;
    }
  }
  float acc[4][8];
  #pragma unroll
  for (int i=0;i<4;++i){
    #pragma unroll
    for (int j=0;j<8;++j) acc[i][j]=0.f;
  }
  float rsum[4] = {0.f,0.f,0.f,0.f};

  const float* kg = kbuf + (size_t)b*16384;
  const float* vg = vbuf + (size_t)b*65536;

  for (int mc = 0; mc < 8; ++mc){
    for (int idx = tid; idx < 2048; idx += 512){
      int mm = idx >> 4, a = idx & 15;
      k_s[mm*20 + a] = kg[(size_t)(mc*128+mm)*16 + a];
    }
    for (int idx = tid; idx < 8192; idx += 512){
      int mm = idx >> 6, c = idx & 63;
      v_s[mm*64 + c] = vg[(size_t)(mc*128+mm)*64 + c];
    }
    __syncthreads();
    // scores
    #pragma unroll
    for (int j=0;j<2;++j){
      int m = smg + 64*j;
      float kr[16];
      #pragma unroll
      for (int a4=0;a4<4;++a4){
        float4 kv = *reinterpret_cast<const float4*>(&k_s[m*20 + a4*4]);
        kr[a4*4+0]=kv.x; kr[a4*4+1]=kv.y; kr[a4*4+2]=kv.z; kr[a4*4+3]=kv.w;
      }
      float e4[4];
      #pragma unroll
      for (int i=0;i<4;++i){
        float s = 0.f;
        #pragma unroll
        for (int a=0;a<16;++a) s += qreg[i][a]*kr[a];
        float e = __expf(fminf(s, 60.0f));
        e4[i] = e;
        rsum[i] += e;
      }
      *reinterpret_cast<float4*>(&e_s[m*36 + sng*4]) = make_float4(e4[0],e4[1],e4[2],e4[3]);
    }
    __syncthreads();
    // PV: wave pg handles 16 m's
    #pragma unroll 4
    for (int mm = 0; mm < 16; ++mm){
      int m = pg*16 + mm;
      float4 ev = *reinterpret_cast<const float4*>(&e_s[m*36 + pnq*4]);
      float4 v0 = *reinterpret_cast<const float4*>(&v_s[m*64 + pcq*8]);
      float4 v1 = *reinterpret_cast<const float4*>(&v_s[m*64 + pcq*8 + 4]);
      #pragma unroll
      for (int i=0;i<4;++i){
        float e = (&ev.x)[i];
        acc[i][0] += e*v0.x; acc[i][1] += e*v0.y; acc[i][2] += e*v0.z; acc[i][3] += e*v0.w;
        acc[i][4] += e*v1.x; acc[i][5] += e*v1.y; acc[i][6] += e*v1.z; acc[i][7] += e*v1.w;
      }
    }
    __syncthreads();
  }

  // rsum: all lanes of wave sng hold partials for the same 4 n's
  #pragma unroll
  for (int i=0;i<4;++i){
    float r = rsum[i];
    r += __shfl_xor(r,1); r += __shfl_xor(r,2); r += __shfl_xor(r,4);
    r += __shfl_xor(r,8); r += __shfl_xor(r,16); r += __shfl_xor(r,32);
    if (smg == 0) rinv_s[sng*4+i] = 1.0f/r;
  }

  // tree-reduce 8 wave-partials (red = v_s, 4 x 2048)
  float* red = v_s;
  if (pg >= 4){
    #pragma unroll
    for (int i=0;i<4;++i){
      float* d = &red[(pg-4)*2048 + (pnq*4+i)*64 + pcq*8];
      *reinterpret_cast<float4*>(d)   = make_float4(acc[i][0],acc[i][1],acc[i][2],acc[i][3]);
      *reinterpret_cast<float4*>(d+4) = make_float4(acc[i][4],acc[i][5],acc[i][6],acc[i][7]);
    }
  }
  __syncthreads();
  if (pg < 4){
    #pragma unroll
    for (int i=0;i<4;++i){
      const float* s = &red[pg*2048 + (pnq*4+i)*64 + pcq*8];
      float4 r0 = *reinterpret_cast<const float4*>(s);
      float4 r1 = *reinterpret_cast<const float4*>(s+4);
      acc[i][0]+=r0.x; acc[i][1]+=r0.y; acc[i][2]+=r0.z; acc[i][3]+=r0.w;
      acc[i][4]+=r1.x; acc[i][5]+=r1.y; acc[i][6]+=r1.z; acc[i][7]+=r1.w;
    }
  }
  __syncthreads();
  if (pg == 2 || pg == 3){
    #pragma unroll
    for (int i=0;i<4;++i){
      float* d = &red[(pg-2)*2048 + (pnq*4+i)*64 + pcq*8];
      *reinterpret_cast<float4*>(d)   = make_float4(acc[i][0],acc[i][1],acc[i][2],acc[i][3]);
      *reinterpret_cast<float4*>(d+4) = make_float4(acc[i][4],acc[i][5],acc[i][6],acc[i][7]);
    }
  }
  __syncthreads();
  if (pg < 2){
    #pragma unroll
    for (int i=0;i<4;++i){
      const float* s = &red[pg*2048 + (pnq*4+i)*64 + pcq*8];
      float4 r0 = *reinterpret_cast<const float4*>(s);
      float4 r1 = *reinterpret_cast<const float4*>(s+4);
      acc[i][0]+=r0.x; acc[i][1]+=r0.y; acc[i][2]+=r0.z; acc[i][3]+=r0.w;
      acc[i][4]+=r1.x; acc[i][5]+=r1.y; acc[i][6]+=r1.z; acc[i][7]+=r1.w;
    }
  }
  __syncthreads();
  if (pg == 1){
    #pragma unroll
    for (int i=0;i<4;++i){
      float* d = &red[(pnq*4+i)*64 + pcq*8];
      *reinterpret_cast<float4*>(d)   = make_float4(acc[i][0],acc[i][1],acc[i][2],acc[i][3]);
      *reinterpret_cast<float4*>(d+4) = make_float4(acc[i][4],acc[i][5],acc[i][6],acc[i][7]);
    }
  }
  __syncthreads();
  float* tb = e_s;   // [c][33n]
  if (pg == 0){
    #pragma unroll
    for (int i=0;i<4;++i){
      int n = pnq*4+i;
      const float* s = &red[n*64 + pcq*8];
      float4 r0 = *reinterpret_cast<const float4*>(s);
      float4 r1 = *reinterpret_cast<const float4*>(s+4);
      float inv = rinv_s[n];
      #pragma unroll
      for (int j=0;j<4;++j){
        tb[(pcq*8+j)*33 + n]   = (acc[i][j]   + (&r0.x)[j]) * inv;
        tb[(pcq*8+4+j)*33 + n] = (acc[i][4+j] + (&r1.x)[j]) * inv;
      }
    }
  }
  __syncthreads();
  float* zout = zcat + ((size_t)b*128 + br*64)*1024;
  for (int idx = tid; idx < 2048; idx += 512){
    int nn = idx & 31, ch = idx >> 5;
    zout[(size_t)ch*1024 + n0 + nn] = tb[ch*33 + nn];
  }
}

// ---------------------------------------------------------------------------
// zcomb: zt = zwT^T@zcat+z_b; comb = mw4@[zt;hnew]+m_b; gate; h_out
// grid (128 tiles of 8px, 4 b) = 512 blocks; block 256 = 8px x 32lr
// ---------------------------------------------------------------------------
__global__ __launch_bounds__(256) void k_zcomb(
  const float* __restrict__ zcat, const float* __restrict__ hnew,
  const float* __restrict__ smalls, const float* __restrict__ zwT,
  const float* __restrict__ mw4, const int* __restrict__ flagp,
  float* __restrict__ mst, float* __restrict__ hstate,
  void* __restrict__ outraw, int t)
{
  __shared__ float zin[128*9];
  __shared__ float hl [64*9];
  __shared__ float ml [64*9];
  __shared__ float zt_s[8*132];
  __shared__ float ho_s[64*9];
  __shared__ float mn_s[64*9];
  int n0 = blockIdx.x*8, b = blockIdx.y;
  int tid = threadIdx.x;
  int px = tid >> 5, lr = tid & 31;
  int flag = *flagp;
  for (int idx = tid; idx < 1024; idx += 256){
    int ch = idx >> 3, pp = idx & 7;
    zin[ch*9+pp] = zcat[((size_t)b*128 + ch)*1024 + n0 + pp];
  }
  for (int idx = tid; idx < 512; idx += 256){
    int ch = idx >> 3, pp = idx & 7;
    hl[ch*9+pp] = hnew[((size_t)b*64 + ch)*1024 + n0 + pp];
    ml[ch*9+pp] = mst [((size_t)b*64 + ch)*1024 + n0 + pp];
  }
  __syncthreads();
  // phase 1: zt rows r = lr*4..lr*4+3
  {
    float4 a4 = *reinterpret_cast<const float4*>(&smalls[O_ZB + lr*4]);
    float acc0=a4.x, acc1=a4.y, acc2=a4.z, acc3=a4.w;
    #pragma unroll 4
    for (int k = 0; k < 128; ++k){
      float zv = zin[k*9 + px];
      float4 w4 = *reinterpret_cast<const float4*>(&zwT[k*128 + lr*4]);
      acc0 += w4.x*zv; acc1 += w4.y*zv; acc2 += w4.z*zv; acc3 += w4.w*zv;
    }
    *reinterpret_cast<float4*>(&zt_s[px*132 + lr*4]) = make_float4(acc0,acc1,acc2,acc3);
  }
  __syncthreads();
  // phase 2: comb rows r = lr + 32i (k4-packed float4 weight loads)
  {
    float acc6[6];
    #pragma unroll
    for (int i=0;i<6;++i) acc6[i] = smalls[O_MB + lr + 32*i];
    #pragma unroll 2
    for (int k4 = 0; k4 < 32; ++k4){
      float4 xv = *reinterpret_cast<const float4*>(&zt_s[px*132 + k4*4]);
      const float* wb = mw4 + (size_t)(k4*192)*4;
      #pragma unroll
      for (int i=0;i<6;++i){
        float4 w = *reinterpret_cast<const float4*>(&wb[(lr + 32*i)*4]);
        acc6[i] += w.x*xv.x + w.y*xv.y + w.z*xv.z + w.w*xv.w;
      }
    }
    #pragma unroll 2
    for (int k4 = 32; k4 < 48; ++k4){
      int ch = (k4-32)*4;
      float4 xv = make_float4(hl[ch*9+px], hl[(ch+1)*9+px], hl[(ch+2)*9+px], hl[(ch+3)*9+px]);
      const float* wb = mw4 + (size_t)(k4*192)*4;
      #pragma unroll
      for (int i=0;i<6;++i){
        float4 w = *reinterpret_cast<const float4*>(&wb[(lr + 32*i)*4]);
        acc6[i] += w.x*xv.x + w.y*xv.y + w.z*xv.z + w.w*xv.w;
      }
    }
    #pragma unroll
    for (int j=0;j<2;++j){
      int ch = lr + 32*j;
      float mold = ml[ch*9 + px];
      float gi = sigm(acc6[4+j]);
      float mnew = (1.0f-gi)*mold + gi*tanhc(acc6[2+j]);
      float ho = sigm(acc6[j])*mnew;
      ho_s[ch*9+px] = ho;
      mn_s[ch*9+px] = mnew;
    }
  }
  __syncthreads();
  for (int idx = tid; idx < 512; idx += 256){
    int ch = idx >> 3, pp = idx & 7;
    int n = n0 + pp;
    size_t gidx = ((size_t)b*64 + ch)*1024 + n;
    mst[gidx] = mn_s[ch*9+pp];
    float ho = ho_s[ch*9+pp];
    hstate[gidx] = ho;
    size_t oidx = ((size_t)(b*64+ch)*8 + t)*1024 + n;
    if (flag) ((float*)outraw)[oidx] = ho;
    else      ((bf16*)outraw)[oidx] = __float2bfloat16(ho);
  }
}

extern "C" void kernel_launch(void* const* d_in, const int* in_sizes, int n_in,
                              void* d_out, int out_size, void* d_ws, size_t ws_size,
                              hipStream_t stream)
{
  float* ws = (float*)d_ws;
  int* flag = (int*)(ws + WS_FLAG);
  float* h    = ws + WS_H;
  float* c    = ws + WS_C;
  float* m    = ws + WS_M;
  float* hnew = ws + WS_HNEW;
  float* wre  = ws + WS_WRE;
  float* qb   = ws + WS_QB;
  float* khb  = ws + WS_KHB;
  float* kmb  = ws + WS_KMB;
  float* vhb  = ws + WS_VHB;
  float* vmb  = ws + WS_VMB;
  float* zcat = ws + WS_ZCAT;
  float* zwT  = ws + WS_ZWT;
  float* mw4  = ws + WS_MW4;

  k_probe<<<1, 256, 0, stream>>>((const unsigned int*)d_in[0], flag);
  P18 pk;
  for (int i = 0; i < 18; ++i) pk.p[i] = d_in[2 + i];
  k_wconv<<<dim3(64,18), 256, 0, stream>>>(pk, flag, ws);
  k_init<<<3072, 256, 0, stream>>>(d_in[1], flag, ws);
  k_wtrans<<<144, 256, 0, stream>>>(ws);

  for (int t = 0; t < 8; ++t){
    k_conv_lstm<<<dim3(8,16,4), 256, 0, stream>>>(flag, d_in[0], wre, ws, h, c, hnew, t);
    k_proj<<<dim3(64,4), 256, 0, stream>>>(hnew, m, ws, qb, khb, kmb, vhb, vmb);
    k_fatt<<<dim3(32,4,2), 512, 0, stream>>>(qb, khb, kmb, vhb, vmb, zcat);
    k_zcomb<<<dim3(128,4), 256, 0, stream>>>(zcat, hnew, ws, zwT, mw4, flag, m, h, d_out, t);
  }
  (void)in_sizes; (void)n_in; (void)out_size; (void)ws_size;
}

// Round 5
// 1188.543 us; speedup vs baseline: 2.6681x; 1.2716x over previous
//
#include <hip/hip_runtime.h>
#include <hip/hip_bf16.h>

typedef __hip_bfloat16 bf16;
typedef unsigned short ushort;
typedef __attribute__((ext_vector_type(8))) short short8v;   // 8 bf16 = 4 VGPR
typedef __attribute__((ext_vector_type(4))) float float4v;

__device__ __forceinline__ float b2f(bf16 v){ return __bfloat162float(v); }
__device__ __forceinline__ float sigm(float x){ return 1.0f/(1.0f+__expf(-x)); }
__device__ __forceinline__ float tanhc(float x){
  x = fminf(15.0f, fmaxf(-15.0f, x));
  float e = __expf(2.0f*x);
  return (e-1.0f)/(e+1.0f);
}
__device__ __forceinline__ ushort f2bu(float f){
  bf16 h = __float2bfloat16(f); return *reinterpret_cast<ushort*>(&h);
}
__device__ __forceinline__ float bu2f(ushort u){
  return __uint_as_float(((unsigned)u)<<16);
}
__device__ __forceinline__ short8v ldfrag(const ushort* p){
  return *reinterpret_cast<const short8v*>(p);
}

// ---------------------------------------------------------------------------
// ws layout (float offsets)
// ---------------------------------------------------------------------------
#define WS_SMALL   0          // 262144 f32 small weights
#define WS_FLAG    262144
#define WS_H       262208     // 786432: h,c,m f32 states (h slot kept for zeroing)
#define WS_C       524352
#define WS_M       786496
#define WS_HNEW    1048640    // 262144 f32 cell output h_new
#define WS_QB      1310784    // 65536
#define WS_KHB     1376320    // 65536
#define WS_KMB     1441856    // 65536
#define WS_VHB     1507392    // 262144
#define WS_VMB     1769536    // 262144
#define WS_ZCAT    2031680    // 524288
#define WS_ZWT     2555968    // 16384
#define WS_MW4     2572352    // 36864
#define WS_WAHI    2609216    // 294912 bf16 (147456 f)  wA[p][cc*4+g][ci]
#define WS_WALO    2756672    // 294912 bf16
#define WS_XTHI    2904128    // 2097152 bf16 (1048576 f) XT[b][t][px][ci]
#define WS_XTLO    3952704
#define WS_HTHI    5001280    // 262144 bf16 (131072 f)  hT[b][px][ci]
#define WS_HTLO    5132352    // total 5263424 f = 21.1 MB
// small-weight offsets inside WS_SMALL
#define O_CB    0
#define O_WCI   256
#define O_WCF   65792
#define O_WCO   131328
#define O_QW    196864
#define O_QB    197888
#define O_KW    197904
#define O_KB    198928
#define O_K2W   198944
#define O_K2B   199968
#define O_VW    199984
#define O_VB    204080
#define O_V2W   204144
#define O_V2B   208240
#define O_ZW    208304
#define O_ZB    224688
#define O_MW    224816
#define O_MB    261680

// ---------------------------------------------------------------------------
// dtype probe (f32 vs bf16 input data)
// ---------------------------------------------------------------------------
__global__ void k_probe(const unsigned int* __restrict__ Xu, int* __restrict__ flag){
  __shared__ int cnt;
  if (threadIdx.x == 0) cnt = 0;
  __syncthreads();
  unsigned int u = Xu[threadIdx.x];
  float f = __uint_as_float((u & 0xffffu) << 16);
  int bad = (fabsf(f) <= 1e4f) ? 0 : 1;
  atomicAdd(&cnt, bad);
  __syncthreads();
  if (threadIdx.x == 0) *flag = (cnt > 16) ? 1 : 0;
}

// ---------------------------------------------------------------------------
// convert the 18 small inputs into f32 copies in ws
// ---------------------------------------------------------------------------
struct P18 { const void* p[18]; };

__global__ __launch_bounds__(256) void k_wconv(P18 pk, const int* __restrict__ flagp,
                                               float* __restrict__ dst){
  const int ns[18]   = {256,65536,65536,65536,1024,16,1024,16,1024,16,
                        4096,64,4096,64,16384,128,36864,192};
  const int offs[18] = {O_CB,O_WCI,O_WCF,O_WCO,O_QW,O_QB,O_KW,O_KB,O_K2W,O_K2B,
                        O_VW,O_VB,O_V2W,O_V2B,O_ZW,O_ZB,O_MW,O_MB};
  int y = blockIdx.y;
  int n = ns[y];
  int flag = *flagp;
  const void* src = pk.p[y];
  for (int i = blockIdx.x*256 + threadIdx.x; i < n; i += gridDim.x*256){
    float v = flag ? ((const float*)src)[i] : b2f(((const bf16*)src)[i]);
    dst[offs[y] + i] = v;
  }
}

// transpose z_w into [k][r]; pack m_w into mw4[(k4*192 + r)*4 + q]
__global__ __launch_bounds__(256) void k_wtrans(float* __restrict__ ws){
  int i = blockIdx.x*256 + threadIdx.x;
  if (i < 16384){
    int k = i >> 7, r = i & 127;
    ws[WS_ZWT + k*128 + r] = ws[O_ZW + r*128 + k];
  }
  if (i < 36864){
    int q = i & 3; int rest = i >> 2; int r = rest % 192; int k4 = rest / 192;
    ws[WS_MW4 + i] = ws[O_MW + r*192 + k4*4 + q];
  }
}

// ---------------------------------------------------------------------------
// init: zero h,c,m + hT; build MFMA weight layout wA (hi/lo)
// wA[(p*256 + cc*4 + g)*128 + ci] = conv_w[((g*64+cc)*128+ci)*9 + p]
// ---------------------------------------------------------------------------
__global__ __launch_bounds__(256) void k_init(const void* __restrict__ conv_w,
                                              const int* __restrict__ flagp,
                                              float* __restrict__ ws){
  int i = blockIdx.x*256 + threadIdx.x;
  int flag = *flagp;
  if (i < 786432) ws[WS_H + i] = 0.0f;
  if (i < 294912){
    int ci = i & 127;
    int j = i >> 7;
    int mm = j & 255, p = j >> 8;
    int cc = mm >> 2, g = mm & 3;
    int si = ((g*64 + cc)*128 + ci)*9 + p;
    ushort* wah = (ushort*)(ws + WS_WAHI);
    ushort* wal = (ushort*)(ws + WS_WALO);
    if (flag){
      float f = ((const float*)conv_w)[si];
      ushort hi = f2bu(f);
      wah[i] = hi;
      wal[i] = f2bu(f - bu2f(hi));
    } else {
      wah[i] = ((const ushort*)conv_w)[si];
    }
  }
  if (i < 131072){
    ((unsigned*)(ws + WS_HTHI))[i] = 0u;
    ((unsigned*)(ws + WS_HTLO))[i] = 0u;
  }
}

// ---------------------------------------------------------------------------
// X transpose: XT[b][t][px][ci] (bf16 hi, + lo if f32 inputs)
// grid (16 px-tiles, 32 b*t slices), block 256
// ---------------------------------------------------------------------------
__global__ __launch_bounds__(256) void k_xt(const void* __restrict__ Xraw,
                                            const int* __restrict__ flagp,
                                            float* __restrict__ ws){
  __shared__ ushort hi_s[64][66];
  __shared__ ushort lo_s[64][66];
  int pt = blockIdx.x, s = blockIdx.y;
  int b = s >> 3, t = s & 7;
  int flag = *flagp;
  int tid = threadIdx.x;
  for (int k = 0; k < 16; ++k){
    int idx = tid + k*256;
    int ci = idx >> 6, pxl = idx & 63;
    size_t si = ((size_t)(b*64 + ci)*8 + t)*1024 + pt*64 + pxl;
    if (flag){
      float f = ((const float*)Xraw)[si];
      ushort h = f2bu(f);
      hi_s[pxl][ci] = h;
      lo_s[pxl][ci] = f2bu(f - bu2f(h));
    } else {
      hi_s[pxl][ci] = ((const ushort*)Xraw)[si];
    }
  }
  __syncthreads();
  ushort* xh = (ushort*)(ws + WS_XTHI) + ((size_t)s*1024 + pt*64)*64;
  ushort* xl = (ushort*)(ws + WS_XTLO) + ((size_t)s*1024 + pt*64)*64;
  for (int k = 0; k < 16; ++k){
    int idx = tid + k*256;
    int pxl = idx >> 6, ci = idx & 63;
    xh[pxl*64 + ci] = hi_s[pxl][ci];
    if (flag) xl[pxl*64 + ci] = lo_s[pxl][ci];
  }
}

// ---------------------------------------------------------------------------
// conv 3x3 + peephole LSTM via MFMA implicit GEMM (9 shifted 1x1 passes).
// grid (4 mblk, 16 nblk, 4 b), block 256 = 4 waves.
// wave: M=64 (rows = cc*4+g perm), N=16 px (n0 = nblk*64 + wave*16).
// K per p: X(64 ci) exact-bf16, h_hi(64), h_lo(64)  [flag1 adds lo passes]
// acc regs (D col=lane&15, row=(lane>>4)*4+reg) => reg = gate g, thread-local
// LSTM pointwise. Boundary shifts handled by per-lane B-frag predication.
// ---------------------------------------------------------------------------
__global__ __launch_bounds__(256) void k_conv_mfma(
  const int* __restrict__ flagp,
  const ushort* __restrict__ wa_hi, const ushort* __restrict__ wa_lo,
  const ushort* __restrict__ xt_hi, const ushort* __restrict__ xt_lo,
  const ushort* __restrict__ ht_hi, const ushort* __restrict__ ht_lo,
  const float* __restrict__ smalls, float* __restrict__ cst,
  float* __restrict__ hnew, int t)
{
  int mblk = blockIdx.x, nblk = blockIdx.y, b = blockIdx.z;
  int tid = threadIdx.x;
  int wave = tid >> 6, lane = tid & 63;
  int lr = lane & 15, lk = lane >> 4;
  int flag = *flagp;
  int n0 = nblk*64 + wave*16;
  int px = n0 + lr, y = px >> 5, x = px & 31;
  int m0 = mblk*64;
  const ushort* xb  = xt_hi + ((size_t)(b*8 + t))*65536;
  const ushort* xlb = xt_lo + ((size_t)(b*8 + t))*65536;
  const ushort* hb  = ht_hi + (size_t)b*65536;
  const ushort* hlb = ht_lo + (size_t)b*65536;
  const short8v ZF = {0,0,0,0,0,0,0,0};

  float4v acc[4];
  #pragma unroll
  for (int mf=0; mf<4; ++mf) acc[mf] = (float4v){0.f,0.f,0.f,0.f};

  #pragma unroll 1
  for (int p = 0; p < 9; ++p){
    int dy = p/3 - 1, dx = p%3 - 1;
    int py = y + dy, xx = x + dx;
    bool valid = (py >= 0) & (py < 32) & (xx >= 0) & (xx < 32);
    int pin = valid ? (py*32 + xx) : 0;
    int boff = pin*64 + lk*8;

    short8v AX[4][2], AH[4][2];
    #pragma unroll
    for (int mf=0; mf<4; ++mf){
      const ushort* ar = wa_hi + (size_t)(p*256 + m0 + mf*16 + lr)*128 + lk*8;
      AX[mf][0] = ldfrag(ar);      AX[mf][1] = ldfrag(ar + 32);
      AH[mf][0] = ldfrag(ar + 64); AH[mf][1] = ldfrag(ar + 96);
    }
    short8v BX[2], BH[2], BL[2];
    BX[0] = ldfrag(xb + boff);   BX[1] = ldfrag(xb + boff + 32);
    BH[0] = ldfrag(hb + boff);   BH[1] = ldfrag(hb + boff + 32);
    BL[0] = ldfrag(hlb + boff);  BL[1] = ldfrag(hlb + boff + 32);
    if (!valid){
      BX[0]=ZF; BX[1]=ZF; BH[0]=ZF; BH[1]=ZF; BL[0]=ZF; BL[1]=ZF;
    }
    #pragma unroll
    for (int kh=0; kh<2; ++kh){
      #pragma unroll
      for (int mf=0; mf<4; ++mf){
        acc[mf] = __builtin_amdgcn_mfma_f32_16x16x32_bf16(AX[mf][kh], BX[kh], acc[mf], 0,0,0);
        acc[mf] = __builtin_amdgcn_mfma_f32_16x16x32_bf16(AH[mf][kh], BH[kh], acc[mf], 0,0,0);
        acc[mf] = __builtin_amdgcn_mfma_f32_16x16x32_bf16(AH[mf][kh], BL[kh], acc[mf], 0,0,0);
      }
    }
    if (flag){
      // f32-input extra passes: wlo*xhi, whi*xlo, wlo*hhi
      short8v AXl[4][2], AHl[4][2];
      #pragma unroll
      for (int mf=0; mf<4; ++mf){
        const ushort* ar = wa_lo + (size_t)(p*256 + m0 + mf*16 + lr)*128 + lk*8;
        AXl[mf][0] = ldfrag(ar);      AXl[mf][1] = ldfrag(ar + 32);
        AHl[mf][0] = ldfrag(ar + 64); AHl[mf][1] = ldfrag(ar + 96);
      }
      short8v BXl[2];
      BXl[0] = ldfrag(xlb + boff); BXl[1] = ldfrag(xlb + boff + 32);
      if (!valid){ BXl[0]=ZF; BXl[1]=ZF; }
      #pragma unroll
      for (int kh=0; kh<2; ++kh){
        #pragma unroll
        for (int mf=0; mf<4; ++mf){
          acc[mf] = __builtin_amdgcn_mfma_f32_16x16x32_bf16(AXl[mf][kh], BX[kh],  acc[mf], 0,0,0);
          acc[mf] = __builtin_amdgcn_mfma_f32_16x16x32_bf16(AX[mf][kh],  BXl[kh], acc[mf], 0,0,0);
          acc[mf] = __builtin_amdgcn_mfma_f32_16x16x32_bf16(AHl[mf][kh], BH[kh],  acc[mf], 0,0,0);
        }
      }
    }
  }

  // epilogue: bias + peephole LSTM, thread-local (reg = gate)
  #pragma unroll
  for (int mf=0; mf<4; ++mf){
    int cc = mblk*16 + mf*4 + lk;
    int wi = cc*1024 + px;
    size_t sidx = ((size_t)(b*64 + cc))*1024 + px;
    float cprev = cst[sidx];
    float ic = acc[mf][0] + smalls[O_CB + cc];
    float fc = acc[mf][1] + smalls[O_CB + 64 + cc];
    float gc = acc[mf][2] + smalls[O_CB + 128 + cc];
    float oc = acc[mf][3] + smalls[O_CB + 192 + cc];
    float ig = sigm(ic + smalls[O_WCI + wi]*cprev);
    float fg = sigm(fc + smalls[O_WCF + wi]*cprev);
    float cnew = fg*cprev + ig*tanhc(gc);
    float og = sigm(oc + smalls[O_WCO + wi]*cnew);
    cst[sidx]  = cnew;
    hnew[sidx] = og*tanhc(cnew);
  }
}

// ---------------------------------------------------------------------------
// 1x1 projections q,kh (hnew), km (m), vh (hnew), vm (m)
// ---------------------------------------------------------------------------
__global__ __launch_bounds__(256) void k_proj(
  const float* __restrict__ hnew, const float* __restrict__ mst,
  const float* __restrict__ smalls,
  float* __restrict__ qb, float* __restrict__ khb, float* __restrict__ kmb,
  float* __restrict__ vhb, float* __restrict__ vmb)
{
  __shared__ float hs[64*17];
  __shared__ float ms[64*17];
  int b = blockIdx.y, n0 = blockIdx.x*16;
  int tid = threadIdx.x, nl = tid&15, rg = tid>>4;
  for (int idx = tid; idx < 1024; idx += 256){
    int nn = idx & 15, ch = idx >> 4;
    hs[ch*17+nn] = hnew[((size_t)b*64+ch)*1024 + n0 + nn];
    ms[ch*17+nn] = mst [((size_t)b*64+ch)*1024 + n0 + nn];
  }
  __syncthreads();
  int n = n0 + nl;
  for (int j = 0; j < 11; ++j){
    int r = rg + 16*j;
    const float* src; const float* wrow; float bias; float* dst;
    if (r < 16)      { src = hs; wrow = smalls+O_QW  + r*64;        bias = smalls[O_QB+r];        dst = qb  + ((size_t)b*1024+n)*16 + r; }
    else if (r < 32) { int rr=r-16;  src = hs; wrow = smalls+O_KW  + rr*64; bias = smalls[O_KB+rr];  dst = khb + ((size_t)b*1024+n)*16 + rr; }
    else if (r < 48) { int rr=r-32;  src = ms; wrow = smalls+O_K2W + rr*64; bias = smalls[O_K2B+rr]; dst = kmb + ((size_t)b*1024+n)*16 + rr; }
    else if (r < 112){ int rr=r-48;  src = hs; wrow = smalls+O_VW  + rr*64; bias = smalls[O_VB+rr];  dst = vhb + ((size_t)b*1024+n)*64 + rr; }
    else             { int rr=r-112; src = ms; wrow = smalls+O_V2W + rr*64; bias = smalls[O_V2B+rr]; dst = vmb + ((size_t)b*1024+n)*64 + rr; }
    float acc = bias;
    #pragma unroll
    for (int c4 = 0; c4 < 16; ++c4){
      float4 w4 = *reinterpret_cast<const float4*>(wrow + c4*4);
      acc += w4.x*src[(c4*4+0)*17+nl] + w4.y*src[(c4*4+1)*17+nl]
           + w4.z*src[(c4*4+2)*17+nl] + w4.w*src[(c4*4+3)*17+nl];
    }
    *dst = acc;
  }
}

// ---------------------------------------------------------------------------
// fused flash attention (both branches), unnormalized exp + final 1/rowsum
// grid (32 ntiles, 4 b, 2 br), block 512 = 8 waves
// ---------------------------------------------------------------------------
__global__ __launch_bounds__(512) void k_fatt(
  const float* __restrict__ qb, const float* __restrict__ khb, const float* __restrict__ kmb,
  const float* __restrict__ vhb, const float* __restrict__ vmb,
  float* __restrict__ zcat)
{
  __shared__ float k_s[128*20];
  __shared__ float v_s[128*64];
  __shared__ float e_s[128*36];
  __shared__ float q_s[32*20];
  __shared__ float rinv_s[32];
  int n0 = blockIdx.x*32, b = blockIdx.y, br = blockIdx.z;
  const float* kbuf = br ? kmb : khb;
  const float* vbuf = br ? vmb : vhb;
  int tid = threadIdx.x;
  int sng = tid >> 6;
  int smg = tid & 63;
  int pg  = sng;
  int pnq = (tid >> 3) & 7;
  int pcq = tid & 7;

  {
    int nn = tid >> 4, a = tid & 15;
    q_s[nn*20 + a] = qb[((size_t)b*1024 + n0 + nn)*16 + a];
  }
  __syncthreads();
  float qreg[4][16];
  #pragma unroll
  for (int i=0;i<4;++i){
    #pragma unroll
    for (int a4=0;a4<4;++a4){
      float4 v = *reinterpret_cast<const float4*>(&q_s[(sng*4+i)*20 + a4*4]);
      qreg[i][a4*4+0]=v.x; qreg[i][a4*4+1]=v.y; qreg[i][a4*4+2]=v.z; qreg[i][a4*4+3]=v.w;
    }
  }
  float acc[4][8];
  #pragma unroll
  for (int i=0;i<4;++i){
    #pragma unroll
    for (int j=0;j<8;++j) acc[i][j]=0.f;
  }
  float rsum[4] = {0.f,0.f,0.f,0.f};

  const float* kg = kbuf + (size_t)b*16384;
  const float* vg = vbuf + (size_t)b*65536;

  for (int mc = 0; mc < 8; ++mc){
    for (int idx = tid; idx < 2048; idx += 512){
      int mm = idx >> 4, a = idx & 15;
      k_s[mm*20 + a] = kg[(size_t)(mc*128+mm)*16 + a];
    }
    for (int idx = tid; idx < 8192; idx += 512){
      int mm = idx >> 6, c = idx & 63;
      v_s[mm*64 + c] = vg[(size_t)(mc*128+mm)*64 + c];
    }
    __syncthreads();
    #pragma unroll
    for (int j=0;j<2;++j){
      int m = smg + 64*j;
      float kr[16];
      #pragma unroll
      for (int a4=0;a4<4;++a4){
        float4 kv = *reinterpret_cast<const float4*>(&k_s[m*20 + a4*4]);
        kr[a4*4+0]=kv.x; kr[a4*4+1]=kv.y; kr[a4*4+2]=kv.z; kr[a4*4+3]=kv.w;
      }
      float e4[4];
      #pragma unroll
      for (int i=0;i<4;++i){
        float s = 0.f;
        #pragma unroll
        for (int a=0;a<16;++a) s += qreg[i][a]*kr[a];
        float e = __expf(fminf(s, 60.0f));
        e4[i] = e;
        rsum[i] += e;
      }
      *reinterpret_cast<float4*>(&e_s[m*36 + sng*4]) = make_float4(e4[0],e4[1],e4[2],e4[3]);
    }
    __syncthreads();
    #pragma unroll 4
    for (int mm = 0; mm < 16; ++mm){
      int m = pg*16 + mm;
      float4 ev = *reinterpret_cast<const float4*>(&e_s[m*36 + pnq*4]);
      float4 v0 = *reinterpret_cast<const float4*>(&v_s[m*64 + pcq*8]);
      float4 v1 = *reinterpret_cast<const float4*>(&v_s[m*64 + pcq*8 + 4]);
      #pragma unroll
      for (int i=0;i<4;++i){
        float e = (&ev.x)[i];
        acc[i][0] += e*v0.x; acc[i][1] += e*v0.y; acc[i][2] += e*v0.z; acc[i][3] += e*v0.w;
        acc[i][4] += e*v1.x; acc[i][5] += e*v1.y; acc[i][6] += e*v1.z; acc[i][7] += e*v1.w;
      }
    }
    __syncthreads();
  }

  #pragma unroll
  for (int i=0;i<4;++i){
    float r = rsum[i];
    r += __shfl_xor(r,1); r += __shfl_xor(r,2); r += __shfl_xor(r,4);
    r += __shfl_xor(r,8); r += __shfl_xor(r,16); r += __shfl_xor(r,32);
    if (smg == 0) rinv_s[sng*4+i] = 1.0f/r;
  }

  float* red = v_s;
  if (pg >= 4){
    #pragma unroll
    for (int i=0;i<4;++i){
      float* d = &red[(pg-4)*2048 + (pnq*4+i)*64 + pcq*8];
      *reinterpret_cast<float4*>(d)   = make_float4(acc[i][0],acc[i][1],acc[i][2],acc[i][3]);
      *reinterpret_cast<float4*>(d+4) = make_float4(acc[i][4],acc[i][5],acc[i][6],acc[i][7]);
    }
  }
  __syncthreads();
  if (pg < 4){
    #pragma unroll
    for (int i=0;i<4;++i){
      const float* s = &red[pg*2048 + (pnq*4+i)*64 + pcq*8];
      float4 r0 = *reinterpret_cast<const float4*>(s);
      float4 r1 = *reinterpret_cast<const float4*>(s+4);
      acc[i][0]+=r0.x; acc[i][1]+=r0.y; acc[i][2]+=r0.z; acc[i][3]+=r0.w;
      acc[i][4]+=r1.x; acc[i][5]+=r1.y; acc[i][6]+=r1.z; acc[i][7]+=r1.w;
    }
  }
  __syncthreads();
  if (pg == 2 || pg == 3){
    #pragma unroll
    for (int i=0;i<4;++i){
      float* d = &red[(pg-2)*2048 + (pnq*4+i)*64 + pcq*8];
      *reinterpret_cast<float4*>(d)   = make_float4(acc[i][0],acc[i][1],acc[i][2],acc[i][3]);
      *reinterpret_cast<float4*>(d+4) = make_float4(acc[i][4],acc[i][5],acc[i][6],acc[i][7]);
    }
  }
  __syncthreads();
  if (pg < 2){
    #pragma unroll
    for (int i=0;i<4;++i){
      const float* s = &red[pg*2048 + (pnq*4+i)*64 + pcq*8];
      float4 r0 = *reinterpret_cast<const float4*>(s);
      float4 r1 = *reinterpret_cast<const float4*>(s+4);
      acc[i][0]+=r0.x; acc[i][1]+=r0.y; acc[i][2]+=r0.z; acc[i][3]+=r0.w;
      acc[i][4]+=r1.x; acc[i][5]+=r1.y; acc[i][6]+=r1.z; acc[i][7]+=r1.w;
    }
  }
  __syncthreads();
  if (pg == 1){
    #pragma unroll
    for (int i=0;i<4;++i){
      float* d = &red[(pnq*4+i)*64 + pcq*8];
      *reinterpret_cast<float4*>(d)   = make_float4(acc[i][0],acc[i][1],acc[i][2],acc[i][3]);
      *reinterpret_cast<float4*>(d+4) = make_float4(acc[i][4],acc[i][5],acc[i][6],acc[i][7]);
    }
  }
  __syncthreads();
  float* tb = e_s;
  if (pg == 0){
    #pragma unroll
    for (int i=0;i<4;++i){
      int n = pnq*4+i;
      const float* s = &red[n*64 + pcq*8];
      float4 r0 = *reinterpret_cast<const float4*>(s);
      float4 r1 = *reinterpret_cast<const float4*>(s+4);
      float inv = rinv_s[n];
      #pragma unroll
      for (int j=0;j<4;++j){
        tb[(pcq*8+j)*33 + n]   = (acc[i][j]   + (&r0.x)[j]) * inv;
        tb[(pcq*8+4+j)*33 + n] = (acc[i][4+j] + (&r1.x)[j]) * inv;
      }
    }
  }
  __syncthreads();
  float* zout = zcat + ((size_t)b*128 + br*64)*1024;
  for (int idx = tid; idx < 2048; idx += 512){
    int nn = idx & 31, ch = idx >> 5;
    zout[(size_t)ch*1024 + n0 + nn] = tb[ch*33 + nn];
  }
}

// ---------------------------------------------------------------------------
// zcomb: zt = zwT^T@zcat+z_b; comb = mw4@[zt;hnew]+m_b; gate; h_out
// writes m state, hT_hi/hT_lo (bf16 [px][cc], conv input), and d_out
// grid (128 tiles of 8px, 4 b), block 256 = 8px x 32lr
// ---------------------------------------------------------------------------
__global__ __launch_bounds__(256) void k_zcomb(
  const float* __restrict__ zcat, const float* __restrict__ hnew,
  const float* __restrict__ smalls, const float* __restrict__ zwT,
  const float* __restrict__ mw4, const int* __restrict__ flagp,
  float* __restrict__ mst, ushort* __restrict__ hth, ushort* __restrict__ htl,
  void* __restrict__ outraw, int t)
{
  __shared__ float zin[128*9];
  __shared__ float hl [64*9];
  __shared__ float ml [64*9];
  __shared__ float zt_s[8*132];
  __shared__ float ho_s[64*9];
  __shared__ float mn_s[64*9];
  int n0 = blockIdx.x*8, b = blockIdx.y;
  int tid = threadIdx.x;
  int px = tid >> 5, lr = tid & 31;
  int flag = *flagp;
  for (int idx = tid; idx < 1024; idx += 256){
    int ch = idx >> 3, pp = idx & 7;
    zin[ch*9+pp] = zcat[((size_t)b*128 + ch)*1024 + n0 + pp];
  }
  for (int idx = tid; idx < 512; idx += 256){
    int ch = idx >> 3, pp = idx & 7;
    hl[ch*9+pp] = hnew[((size_t)b*64 + ch)*1024 + n0 + pp];
    ml[ch*9+pp] = mst [((size_t)b*64 + ch)*1024 + n0 + pp];
  }
  __syncthreads();
  {
    float4 a4 = *reinterpret_cast<const float4*>(&smalls[O_ZB + lr*4]);
    float acc0=a4.x, acc1=a4.y, acc2=a4.z, acc3=a4.w;
    #pragma unroll 4
    for (int k = 0; k < 128; ++k){
      float zv = zin[k*9 + px];
      float4 w4 = *reinterpret_cast<const float4*>(&zwT[k*128 + lr*4]);
      acc0 += w4.x*zv; acc1 += w4.y*zv; acc2 += w4.z*zv; acc3 += w4.w*zv;
    }
    *reinterpret_cast<float4*>(&zt_s[px*132 + lr*4]) = make_float4(acc0,acc1,acc2,acc3);
  }
  __syncthreads();
  {
    float acc6[6];
    #pragma unroll
    for (int i=0;i<6;++i) acc6[i] = smalls[O_MB + lr + 32*i];
    #pragma unroll 2
    for (int k4 = 0; k4 < 32; ++k4){
      float4 xv = *reinterpret_cast<const float4*>(&zt_s[px*132 + k4*4]);
      const float* wb = mw4 + (size_t)(k4*192)*4;
      #pragma unroll
      for (int i=0;i<6;++i){
        float4 w = *reinterpret_cast<const float4*>(&wb[(lr + 32*i)*4]);
        acc6[i] += w.x*xv.x + w.y*xv.y + w.z*xv.z + w.w*xv.w;
      }
    }
    #pragma unroll 2
    for (int k4 = 32; k4 < 48; ++k4){
      int ch = (k4-32)*4;
      float4 xv = make_float4(hl[ch*9+px], hl[(ch+1)*9+px], hl[(ch+2)*9+px], hl[(ch+3)*9+px]);
      const float* wb = mw4 + (size_t)(k4*192)*4;
      #pragma unroll
      for (int i=0;i<6;++i){
        float4 w = *reinterpret_cast<const float4*>(&wb[(lr + 32*i)*4]);
        acc6[i] += w.x*xv.x + w.y*xv.y + w.z*xv.z + w.w*xv.w;
      }
    }
    #pragma unroll
    for (int j=0;j<2;++j){
      int ch = lr + 32*j;
      float mold = ml[ch*9 + px];
      float gi = sigm(acc6[4+j]);
      float mnew = (1.0f-gi)*mold + gi*tanhc(acc6[2+j]);
      float ho = sigm(acc6[j])*mnew;
      ho_s[ch*9+px] = ho;
      mn_s[ch*9+px] = mnew;
    }
  }
  __syncthreads();
  for (int idx = tid; idx < 512; idx += 256){
    int ch = idx >> 3, pp = idx & 7;
    int n = n0 + pp;
    size_t gidx = ((size_t)b*64 + ch)*1024 + n;
    mst[gidx] = mn_s[ch*9+pp];
    float ho = ho_s[ch*9+pp];
    size_t tix = ((size_t)b*1024 + n)*64 + ch;
    ushort hb_ = f2bu(ho);
    hth[tix] = hb_;
    htl[tix] = f2bu(ho - bu2f(hb_));
    size_t oidx = ((size_t)(b*64+ch)*8 + t)*1024 + n;
    if (flag) ((float*)outraw)[oidx] = ho;
    else      ((bf16*)outraw)[oidx] = __float2bfloat16(ho);
  }
}

extern "C" void kernel_launch(void* const* d_in, const int* in_sizes, int n_in,
                              void* d_out, int out_size, void* d_ws, size_t ws_size,
                              hipStream_t stream)
{
  float* ws = (float*)d_ws;
  int* flag = (int*)(ws + WS_FLAG);
  float* c    = ws + WS_C;
  float* m    = ws + WS_M;
  float* hnew = ws + WS_HNEW;
  float* qb   = ws + WS_QB;
  float* khb  = ws + WS_KHB;
  float* kmb  = ws + WS_KMB;
  float* vhb  = ws + WS_VHB;
  float* vmb  = ws + WS_VMB;
  float* zcat = ws + WS_ZCAT;
  float* zwT  = ws + WS_ZWT;
  float* mw4  = ws + WS_MW4;
  ushort* wa_hi = (ushort*)(ws + WS_WAHI);
  ushort* wa_lo = (ushort*)(ws + WS_WALO);
  ushort* xt_hi = (ushort*)(ws + WS_XTHI);
  ushort* xt_lo = (ushort*)(ws + WS_XTLO);
  ushort* ht_hi = (ushort*)(ws + WS_HTHI);
  ushort* ht_lo = (ushort*)(ws + WS_HTLO);

  k_probe<<<1, 256, 0, stream>>>((const unsigned int*)d_in[0], flag);
  P18 pk;
  for (int i = 0; i < 18; ++i) pk.p[i] = d_in[2 + i];
  k_wconv<<<dim3(64,18), 256, 0, stream>>>(pk, flag, ws);
  k_init<<<3072, 256, 0, stream>>>(d_in[1], flag, ws);
  k_xt<<<dim3(16,32), 256, 0, stream>>>(d_in[0], flag, ws);
  k_wtrans<<<144, 256, 0, stream>>>(ws);

  for (int t = 0; t < 8; ++t){
    k_conv_mfma<<<dim3(4,16,4), 256, 0, stream>>>(flag, wa_hi, wa_lo, xt_hi, xt_lo,
                                                  ht_hi, ht_lo, ws, c, hnew, t);
    k_proj<<<dim3(64,4), 256, 0, stream>>>(hnew, m, ws, qb, khb, kmb, vhb, vmb);
    k_fatt<<<dim3(32,4,2), 512, 0, stream>>>(qb, khb, kmb, vhb, vmb, zcat);
    k_zcomb<<<dim3(128,4), 256, 0, stream>>>(zcat, hnew, ws, zwT, mw4, flag,
                                             m, ht_hi, ht_lo, d_out, t);
  }
  (void)in_sizes; (void)n_in; (void)out_size; (void)ws_size;
}

// Round 6
// 952.726 us; speedup vs baseline: 3.3285x; 1.2475x over previous
//
#include <hip/hip_runtime.h>
#include <hip/hip_bf16.h>

typedef __hip_bfloat16 bf16;
typedef unsigned short ushort;
typedef __attribute__((ext_vector_type(8))) short short8v;   // 8 bf16 = 4 VGPR
typedef __attribute__((ext_vector_type(4))) float float4v;

__device__ __forceinline__ float b2f(bf16 v){ return __bfloat162float(v); }
__device__ __forceinline__ float sigm(float x){ return 1.0f/(1.0f+__expf(-x)); }
__device__ __forceinline__ float tanhc(float x){
  x = fminf(15.0f, fmaxf(-15.0f, x));
  float e = __expf(2.0f*x);
  return (e-1.0f)/(e+1.0f);
}
__device__ __forceinline__ ushort f2bu(float f){
  bf16 h = __float2bfloat16(f); return *reinterpret_cast<ushort*>(&h);
}
__device__ __forceinline__ float bu2f(ushort u){
  return __uint_as_float(((unsigned)u)<<16);
}
__device__ __forceinline__ short8v ldfrag(const ushort* p){
  return *reinterpret_cast<const short8v*>(p);
}

// ---------------------------------------------------------------------------
// ws layout (float offsets)
// ---------------------------------------------------------------------------
#define WS_SMALL   0          // 262144 f32 small weights
#define WS_FLAG    262144
#define WS_H       262208     // h,c,m f32 states (h slot legacy-zeroed)
#define WS_C       524352
#define WS_M       786496
#define WS_HNEW    1048640    // 262144 f32 cell output h_new
#define WS_QB16    1310784    // 65536 f = [b][n][32] bf16 zero-padded
#define WS_KHB16   1376320    // 65536
#define WS_KMB16   1441856    // 65536
#define WS_VTH16   1507392    // 131072 f = [b][c][1024] bf16
#define WS_VTM16   1638464    // 131072
#define WS_ZCAT    1769536    // 524288
#define WS_ZWT     2293824    // 16384
#define WS_MW4     2310208    // 36864
#define WS_WAHI    2347072    // 147456 f (294912 bf16)
#define WS_WALO    2494528    // 147456
#define WS_XTHI    2641984    // 1048576
#define WS_XTLO    3690560    // 1048576
#define WS_HTHI    4739136    // 131072
#define WS_HTLO    4870208    // 131072 -> total 5001280 f = 20 MB
// small-weight offsets inside WS_SMALL
#define O_CB    0
#define O_WCI   256
#define O_WCF   65792
#define O_WCO   131328
#define O_QW    196864
#define O_QB    197888
#define O_KW    197904
#define O_KB    198928
#define O_K2W   198944
#define O_K2B   199968
#define O_VW    199984
#define O_VB    204080
#define O_V2W   204144
#define O_V2B   208240
#define O_ZW    208304
#define O_ZB    224688
#define O_MW    224816
#define O_MB    261680

// ---------------------------------------------------------------------------
// dtype probe (f32 vs bf16 input data)
// ---------------------------------------------------------------------------
__global__ void k_probe(const unsigned int* __restrict__ Xu, int* __restrict__ flag){
  __shared__ int cnt;
  if (threadIdx.x == 0) cnt = 0;
  __syncthreads();
  unsigned int u = Xu[threadIdx.x];
  float f = __uint_as_float((u & 0xffffu) << 16);
  int bad = (fabsf(f) <= 1e4f) ? 0 : 1;
  atomicAdd(&cnt, bad);
  __syncthreads();
  if (threadIdx.x == 0) *flag = (cnt > 16) ? 1 : 0;
}

// ---------------------------------------------------------------------------
// convert the 18 small inputs into f32 copies in ws
// ---------------------------------------------------------------------------
struct P18 { const void* p[18]; };

__global__ __launch_bounds__(256) void k_wconv(P18 pk, const int* __restrict__ flagp,
                                               float* __restrict__ dst){
  const int ns[18]   = {256,65536,65536,65536,1024,16,1024,16,1024,16,
                        4096,64,4096,64,16384,128,36864,192};
  const int offs[18] = {O_CB,O_WCI,O_WCF,O_WCO,O_QW,O_QB,O_KW,O_KB,O_K2W,O_K2B,
                        O_VW,O_VB,O_V2W,O_V2B,O_ZW,O_ZB,O_MW,O_MB};
  int y = blockIdx.y;
  int n = ns[y];
  int flag = *flagp;
  const void* src = pk.p[y];
  for (int i = blockIdx.x*256 + threadIdx.x; i < n; i += gridDim.x*256){
    float v = flag ? ((const float*)src)[i] : b2f(((const bf16*)src)[i]);
    dst[offs[y] + i] = v;
  }
}

// transpose z_w into [k][r]; pack m_w into mw4[(k4*192 + r)*4 + q]
__global__ __launch_bounds__(256) void k_wtrans(float* __restrict__ ws){
  int i = blockIdx.x*256 + threadIdx.x;
  if (i < 16384){
    int k = i >> 7, r = i & 127;
    ws[WS_ZWT + k*128 + r] = ws[O_ZW + r*128 + k];
  }
  if (i < 36864){
    int q = i & 3; int rest = i >> 2; int r = rest % 192; int k4 = rest / 192;
    ws[WS_MW4 + i] = ws[O_MW + r*192 + k4*4 + q];
  }
}

// ---------------------------------------------------------------------------
// init: zero h,c,m + hT; build MFMA weight layout wA (hi/lo)
// ---------------------------------------------------------------------------
__global__ __launch_bounds__(256) void k_init(const void* __restrict__ conv_w,
                                              const int* __restrict__ flagp,
                                              float* __restrict__ ws){
  int i = blockIdx.x*256 + threadIdx.x;
  int flag = *flagp;
  if (i < 786432) ws[WS_H + i] = 0.0f;
  if (i < 294912){
    int ci = i & 127;
    int j = i >> 7;
    int mm = j & 255, p = j >> 8;
    int cc = mm >> 2, g = mm & 3;
    int si = ((g*64 + cc)*128 + ci)*9 + p;
    ushort* wah = (ushort*)(ws + WS_WAHI);
    ushort* wal = (ushort*)(ws + WS_WALO);
    if (flag){
      float f = ((const float*)conv_w)[si];
      ushort hi = f2bu(f);
      wah[i] = hi;
      wal[i] = f2bu(f - bu2f(hi));
    } else {
      wah[i] = ((const ushort*)conv_w)[si];
    }
  }
  if (i < 131072){
    ((unsigned*)(ws + WS_HTHI))[i] = 0u;
    ((unsigned*)(ws + WS_HTLO))[i] = 0u;
  }
}

// ---------------------------------------------------------------------------
// X transpose: XT[b][t][px][ci]
// ---------------------------------------------------------------------------
__global__ __launch_bounds__(256) void k_xt(const void* __restrict__ Xraw,
                                            const int* __restrict__ flagp,
                                            float* __restrict__ ws){
  __shared__ ushort hi_s[64][66];
  __shared__ ushort lo_s[64][66];
  int pt = blockIdx.x, s = blockIdx.y;
  int b = s >> 3, t = s & 7;
  int flag = *flagp;
  int tid = threadIdx.x;
  for (int k = 0; k < 16; ++k){
    int idx = tid + k*256;
    int ci = idx >> 6, pxl = idx & 63;
    size_t si = ((size_t)(b*64 + ci)*8 + t)*1024 + pt*64 + pxl;
    if (flag){
      float f = ((const float*)Xraw)[si];
      ushort h = f2bu(f);
      hi_s[pxl][ci] = h;
      lo_s[pxl][ci] = f2bu(f - bu2f(h));
    } else {
      hi_s[pxl][ci] = ((const ushort*)Xraw)[si];
    }
  }
  __syncthreads();
  ushort* xh = (ushort*)(ws + WS_XTHI) + ((size_t)s*1024 + pt*64)*64;
  ushort* xl = (ushort*)(ws + WS_XTLO) + ((size_t)s*1024 + pt*64)*64;
  for (int k = 0; k < 16; ++k){
    int idx = tid + k*256;
    int pxl = idx >> 6, ci = idx & 63;
    xh[pxl*64 + ci] = hi_s[pxl][ci];
    if (flag) xl[pxl*64 + ci] = lo_s[pxl][ci];
  }
}

// ---------------------------------------------------------------------------
// conv 3x3 + peephole LSTM via MFMA implicit GEMM (unchanged from R4)
// ---------------------------------------------------------------------------
__global__ __launch_bounds__(256) void k_conv_mfma(
  const int* __restrict__ flagp,
  const ushort* __restrict__ wa_hi, const ushort* __restrict__ wa_lo,
  const ushort* __restrict__ xt_hi, const ushort* __restrict__ xt_lo,
  const ushort* __restrict__ ht_hi, const ushort* __restrict__ ht_lo,
  const float* __restrict__ smalls, float* __restrict__ cst,
  float* __restrict__ hnew, int t)
{
  int mblk = blockIdx.x, nblk = blockIdx.y, b = blockIdx.z;
  int tid = threadIdx.x;
  int wave = tid >> 6, lane = tid & 63;
  int lr = lane & 15, lk = lane >> 4;
  int flag = *flagp;
  int n0 = nblk*64 + wave*16;
  int px = n0 + lr, y = px >> 5, x = px & 31;
  int m0 = mblk*64;
  const ushort* xb  = xt_hi + ((size_t)(b*8 + t))*65536;
  const ushort* xlb = xt_lo + ((size_t)(b*8 + t))*65536;
  const ushort* hb  = ht_hi + (size_t)b*65536;
  const ushort* hlb = ht_lo + (size_t)b*65536;
  const short8v ZF = {0,0,0,0,0,0,0,0};

  float4v acc[4];
  #pragma unroll
  for (int mf=0; mf<4; ++mf) acc[mf] = (float4v){0.f,0.f,0.f,0.f};

  #pragma unroll 1
  for (int p = 0; p < 9; ++p){
    int dy = p/3 - 1, dx = p%3 - 1;
    int py = y + dy, xx = x + dx;
    bool valid = (py >= 0) & (py < 32) & (xx >= 0) & (xx < 32);
    int pin = valid ? (py*32 + xx) : 0;
    int boff = pin*64 + lk*8;

    short8v AX[4][2], AH[4][2];
    #pragma unroll
    for (int mf=0; mf<4; ++mf){
      const ushort* ar = wa_hi + (size_t)(p*256 + m0 + mf*16 + lr)*128 + lk*8;
      AX[mf][0] = ldfrag(ar);      AX[mf][1] = ldfrag(ar + 32);
      AH[mf][0] = ldfrag(ar + 64); AH[mf][1] = ldfrag(ar + 96);
    }
    short8v BX[2], BH[2], BL[2];
    BX[0] = ldfrag(xb + boff);   BX[1] = ldfrag(xb + boff + 32);
    BH[0] = ldfrag(hb + boff);   BH[1] = ldfrag(hb + boff + 32);
    BL[0] = ldfrag(hlb + boff);  BL[1] = ldfrag(hlb + boff + 32);
    if (!valid){
      BX[0]=ZF; BX[1]=ZF; BH[0]=ZF; BH[1]=ZF; BL[0]=ZF; BL[1]=ZF;
    }
    #pragma unroll
    for (int kh=0; kh<2; ++kh){
      #pragma unroll
      for (int mf=0; mf<4; ++mf){
        acc[mf] = __builtin_amdgcn_mfma_f32_16x16x32_bf16(AX[mf][kh], BX[kh], acc[mf], 0,0,0);
        acc[mf] = __builtin_amdgcn_mfma_f32_16x16x32_bf16(AH[mf][kh], BH[kh], acc[mf], 0,0,0);
        acc[mf] = __builtin_amdgcn_mfma_f32_16x16x32_bf16(AH[mf][kh], BL[kh], acc[mf], 0,0,0);
      }
    }
    if (flag){
      short8v AXl[4][2], AHl[4][2];
      #pragma unroll
      for (int mf=0; mf<4; ++mf){
        const ushort* ar = wa_lo + (size_t)(p*256 + m0 + mf*16 + lr)*128 + lk*8;
        AXl[mf][0] = ldfrag(ar);      AXl[mf][1] = ldfrag(ar + 32);
        AHl[mf][0] = ldfrag(ar + 64); AHl[mf][1] = ldfrag(ar + 96);
      }
      short8v BXl[2];
      BXl[0] = ldfrag(xlb + boff); BXl[1] = ldfrag(xlb + boff + 32);
      if (!valid){ BXl[0]=ZF; BXl[1]=ZF; }
      #pragma unroll
      for (int kh=0; kh<2; ++kh){
        #pragma unroll
        for (int mf=0; mf<4; ++mf){
          acc[mf] = __builtin_amdgcn_mfma_f32_16x16x32_bf16(AXl[mf][kh], BX[kh],  acc[mf], 0,0,0);
          acc[mf] = __builtin_amdgcn_mfma_f32_16x16x32_bf16(AX[mf][kh],  BXl[kh], acc[mf], 0,0,0);
          acc[mf] = __builtin_amdgcn_mfma_f32_16x16x32_bf16(AHl[mf][kh], BH[kh],  acc[mf], 0,0,0);
        }
      }
    }
  }

  #pragma unroll
  for (int mf=0; mf<4; ++mf){
    int cc = mblk*16 + mf*4 + lk;
    int wi = cc*1024 + px;
    size_t sidx = ((size_t)(b*64 + cc))*1024 + px;
    float cprev = cst[sidx];
    float ic = acc[mf][0] + smalls[O_CB + cc];
    float fc = acc[mf][1] + smalls[O_CB + 64 + cc];
    float gc = acc[mf][2] + smalls[O_CB + 128 + cc];
    float oc = acc[mf][3] + smalls[O_CB + 192 + cc];
    float ig = sigm(ic + smalls[O_WCI + wi]*cprev);
    float fg = sigm(fc + smalls[O_WCF + wi]*cprev);
    float cnew = fg*cprev + ig*tanhc(gc);
    float og = sigm(oc + smalls[O_WCO + wi]*cnew);
    cst[sidx]  = cnew;
    hnew[sidx] = og*tanhc(cnew);
  }
}

// ---------------------------------------------------------------------------
// 1x1 projections -> bf16 MFMA-ready buffers:
//   qb16 [b][n][32] (a padded w/ zeros), khb16/kmb16 [b][m][32] padded,
//   vth16/vtm16 [b][c][1024] (transposed V)
// grid (64 ntiles of 16, 4 b), block 256
// ---------------------------------------------------------------------------
__global__ __launch_bounds__(256) void k_proj(
  const float* __restrict__ hnew, const float* __restrict__ mst,
  const float* __restrict__ smalls,
  ushort* __restrict__ qb16, ushort* __restrict__ khb16, ushort* __restrict__ kmb16,
  ushort* __restrict__ vth16, ushort* __restrict__ vtm16)
{
  __shared__ float hs[64*17];
  __shared__ float ms[64*17];
  int b = blockIdx.y, n0 = blockIdx.x*16;
  int tid = threadIdx.x, nl = tid&15, rg = tid>>4;
  for (int idx = tid; idx < 1024; idx += 256){
    int nn = idx & 15, ch = idx >> 4;
    hs[ch*17+nn] = hnew[((size_t)b*64+ch)*1024 + n0 + nn];
    ms[ch*17+nn] = mst [((size_t)b*64+ch)*1024 + n0 + nn];
  }
  __syncthreads();
  int n = n0 + nl;
  for (int j = 0; j < 11; ++j){
    int r = rg + 16*j;
    const float* src; const float* wrow; float bias;
    int mode, rr;
    if (r < 16)      { mode=0; rr=r;     src = hs; wrow = smalls+O_QW  + rr*64; bias = smalls[O_QB+rr]; }
    else if (r < 32) { mode=1; rr=r-16;  src = hs; wrow = smalls+O_KW  + rr*64; bias = smalls[O_KB+rr]; }
    else if (r < 48) { mode=2; rr=r-32;  src = ms; wrow = smalls+O_K2W + rr*64; bias = smalls[O_K2B+rr]; }
    else if (r < 112){ mode=3; rr=r-48;  src = hs; wrow = smalls+O_VW  + rr*64; bias = smalls[O_VB+rr]; }
    else             { mode=4; rr=r-112; src = ms; wrow = smalls+O_V2W + rr*64; bias = smalls[O_V2B+rr]; }
    float acc = bias;
    #pragma unroll
    for (int c4 = 0; c4 < 16; ++c4){
      float4 w4 = *reinterpret_cast<const float4*>(wrow + c4*4);
      acc += w4.x*src[(c4*4+0)*17+nl] + w4.y*src[(c4*4+1)*17+nl]
           + w4.z*src[(c4*4+2)*17+nl] + w4.w*src[(c4*4+3)*17+nl];
    }
    ushort v = f2bu(acc);
    if (mode <= 2){
      ushort* base = (mode==0) ? qb16 : (mode==1) ? khb16 : kmb16;
      size_t o = ((size_t)b*1024 + n)*32;
      base[o + rr] = v;
      base[o + 16 + rr] = 0;
    } else {
      ushort* base = (mode==3) ? vth16 : vtm16;
      base[((size_t)b*64 + rr)*1024 + n] = v;
    }
  }
}

// ---------------------------------------------------------------------------
// MFMA flash attention. grid (32 ntiles of 32, 4 b, 2 br), block 256 = 4 waves.
// scores: A=K[m][32pad] (global b128), B=Q[n][32pad] (regs); D -> exp -> bf16
//   -> b64 LDS write lands P directly in es[n][m] B-frag layout.
// PV: A=VT[c][1024] (global b128), B=P (LDS b128), K-chunks of 256 m.
// es row stride 272 ushort (17 x 16B slots) -> schedulable conflict-free.
// rsum from rounded e; shfl(16,32) + 4-wave LDS reduce; epilogue scales.
// ---------------------------------------------------------------------------
__global__ __launch_bounds__(256) void k_fatt(
  const ushort* __restrict__ qb16, const ushort* __restrict__ khb16,
  const ushort* __restrict__ kmb16, const ushort* __restrict__ vth16,
  const ushort* __restrict__ vtm16, float* __restrict__ zcat)
{
  __shared__ ushort es[2*16*272];
  __shared__ float rs_s[4][2][16];
  int n0 = blockIdx.x*32, b = blockIdx.y, br = blockIdx.z;
  const ushort* kb = (br ? kmb16 : khb16) + (size_t)b*32768;
  const ushort* vt = (br ? vtm16 : vth16) + (size_t)b*65536;
  const ushort* qp = qb16 + (size_t)b*32768;
  int tid = threadIdx.x;
  int w = tid >> 6, lane = tid & 63, lr = lane & 15, lk = lane >> 4;
  const float4v Z4 = {0.f,0.f,0.f,0.f};

  short8v qf[2];
  qf[0] = ldfrag(qp + (size_t)(n0 + lr)*32 + lk*8);
  qf[1] = ldfrag(qp + (size_t)(n0 + 16 + lr)*32 + lk*8);

  float4v acc[2][2];
  acc[0][0]=Z4; acc[0][1]=Z4; acc[1][0]=Z4; acc[1][1]=Z4;
  float rsum[2] = {0.f, 0.f};

  #pragma unroll 1
  for (int mc = 0; mc < 4; ++mc){
    int mbase = mc*256 + w*64;
    #pragma unroll
    for (int tau = 0; tau < 4; ++tau){
      short8v af = ldfrag(kb + (size_t)(mbase + tau*16 + lr)*32 + lk*8);
      #pragma unroll
      for (int ns = 0; ns < 2; ++ns){
        float4v d = __builtin_amdgcn_mfma_f32_16x16x32_bf16(af, qf[ns], Z4, 0,0,0);
        ushort u0 = f2bu(__expf(fminf(d[0], 60.f)));
        ushort u1 = f2bu(__expf(fminf(d[1], 60.f)));
        ushort u2 = f2bu(__expf(fminf(d[2], 60.f)));
        ushort u3 = f2bu(__expf(fminf(d[3], 60.f)));
        rsum[ns] += (bu2f(u0) + bu2f(u1)) + (bu2f(u2) + bu2f(u3));
        unsigned lo = (unsigned)u0 | ((unsigned)u1 << 16);
        unsigned hi = (unsigned)u2 | ((unsigned)u3 << 16);
        *reinterpret_cast<uint2*>(&es[ns*4352 + lr*272 + w*64 + tau*16 + lk*4]) = make_uint2(lo, hi);
      }
    }
    __syncthreads();
    #pragma unroll
    for (int ks = 0; ks < 8; ++ks){
      short8v av = ldfrag(vt + (size_t)(w*16 + lr)*1024 + mc*256 + ks*32 + lk*8);
      #pragma unroll
      for (int ns = 0; ns < 2; ++ns){
        short8v bv = ldfrag(&es[ns*4352 + lr*272 + ks*32 + lk*8]);
        acc[ns][ks & 1] = __builtin_amdgcn_mfma_f32_16x16x32_bf16(av, bv, acc[ns][ks & 1], 0,0,0);
      }
    }
    __syncthreads();
  }

  #pragma unroll
  for (int ns = 0; ns < 2; ++ns){
    float r = rsum[ns];
    r += __shfl_xor(r, 16);
    r += __shfl_xor(r, 32);
    if (lane < 16) rs_s[w][ns][lr] = r;
  }
  __syncthreads();
  #pragma unroll
  for (int ns = 0; ns < 2; ++ns){
    float rinv = 1.0f / (rs_s[0][ns][lr] + rs_s[1][ns][lr] + rs_s[2][ns][lr] + rs_s[3][ns][lr]);
    float4v a;
    #pragma unroll
    for (int r = 0; r < 4; ++r) a[r] = acc[ns][0][r] + acc[ns][1][r];
    #pragma unroll
    for (int r = 0; r < 4; ++r){
      int c = w*16 + lk*4 + r;
      zcat[((size_t)(b*128 + br*64 + c))*1024 + n0 + ns*16 + lr] = a[r]*rinv;
    }
  }
}

// ---------------------------------------------------------------------------
// zcomb: zt = zwT^T@zcat+z_b; comb = mw4@[zt;hnew]+m_b; gate; h_out
// writes m state, hT_hi/lo bf16, and d_out
// ---------------------------------------------------------------------------
__global__ __launch_bounds__(256) void k_zcomb(
  const float* __restrict__ zcat, const float* __restrict__ hnew,
  const float* __restrict__ smalls, const float* __restrict__ zwT,
  const float* __restrict__ mw4, const int* __restrict__ flagp,
  float* __restrict__ mst, ushort* __restrict__ hth, ushort* __restrict__ htl,
  void* __restrict__ outraw, int t)
{
  __shared__ float zin[128*9];
  __shared__ float hl [64*9];
  __shared__ float ml [64*9];
  __shared__ float zt_s[8*132];
  __shared__ float ho_s[64*9];
  __shared__ float mn_s[64*9];
  int n0 = blockIdx.x*8, b = blockIdx.y;
  int tid = threadIdx.x;
  int px = tid >> 5, lr = tid & 31;
  int flag = *flagp;
  for (int idx = tid; idx < 1024; idx += 256){
    int ch = idx >> 3, pp = idx & 7;
    zin[ch*9+pp] = zcat[((size_t)b*128 + ch)*1024 + n0 + pp];
  }
  for (int idx = tid; idx < 512; idx += 256){
    int ch = idx >> 3, pp = idx & 7;
    hl[ch*9+pp] = hnew[((size_t)b*64 + ch)*1024 + n0 + pp];
    ml[ch*9+pp] = mst [((size_t)b*64 + ch)*1024 + n0 + pp];
  }
  __syncthreads();
  {
    float4 a4 = *reinterpret_cast<const float4*>(&smalls[O_ZB + lr*4]);
    float acc0=a4.x, acc1=a4.y, acc2=a4.z, acc3=a4.w;
    #pragma unroll 4
    for (int k = 0; k < 128; ++k){
      float zv = zin[k*9 + px];
      float4 w4 = *reinterpret_cast<const float4*>(&zwT[k*128 + lr*4]);
      acc0 += w4.x*zv; acc1 += w4.y*zv; acc2 += w4.z*zv; acc3 += w4.w*zv;
    }
    *reinterpret_cast<float4*>(&zt_s[px*132 + lr*4]) = make_float4(acc0,acc1,acc2,acc3);
  }
  __syncthreads();
  {
    float acc6[6];
    #pragma unroll
    for (int i=0;i<6;++i) acc6[i] = smalls[O_MB + lr + 32*i];
    #pragma unroll 2
    for (int k4 = 0; k4 < 32; ++k4){
      float4 xv = *reinterpret_cast<const float4*>(&zt_s[px*132 + k4*4]);
      const float* wb = mw4 + (size_t)(k4*192)*4;
      #pragma unroll
      for (int i=0;i<6;++i){
        float4 w = *reinterpret_cast<const float4*>(&wb[(lr + 32*i)*4]);
        acc6[i] += w.x*xv.x + w.y*xv.y + w.z*xv.z + w.w*xv.w;
      }
    }
    #pragma unroll 2
    for (int k4 = 32; k4 < 48; ++k4){
      int ch = (k4-32)*4;
      float4 xv = make_float4(hl[ch*9+px], hl[(ch+1)*9+px], hl[(ch+2)*9+px], hl[(ch+3)*9+px]);
      const float* wb = mw4 + (size_t)(k4*192)*4;
      #pragma unroll
      for (int i=0;i<6;++i){
        float4 w = *reinterpret_cast<const float4*>(&wb[(lr + 32*i)*4]);
        acc6[i] += w.x*xv.x + w.y*xv.y + w.z*xv.z + w.w*xv.w;
      }
    }
    #pragma unroll
    for (int j=0;j<2;++j){
      int ch = lr + 32*j;
      float mold = ml[ch*9 + px];
      float gi = sigm(acc6[4+j]);
      float mnew = (1.0f-gi)*mold + gi*tanhc(acc6[2+j]);
      float ho = sigm(acc6[j])*mnew;
      ho_s[ch*9+px] = ho;
      mn_s[ch*9+px] = mnew;
    }
  }
  __syncthreads();
  for (int idx = tid; idx < 512; idx += 256){
    int ch = idx >> 3, pp = idx & 7;
    int n = n0 + pp;
    size_t gidx = ((size_t)b*64 + ch)*1024 + n;
    mst[gidx] = mn_s[ch*9+pp];
    float ho = ho_s[ch*9+pp];
    size_t tix = ((size_t)b*1024 + n)*64 + ch;
    ushort hb_ = f2bu(ho);
    hth[tix] = hb_;
    htl[tix] = f2bu(ho - bu2f(hb_));
    size_t oidx = ((size_t)(b*64+ch)*8 + t)*1024 + n;
    if (flag) ((float*)outraw)[oidx] = ho;
    else      ((bf16*)outraw)[oidx] = __float2bfloat16(ho);
  }
}

extern "C" void kernel_launch(void* const* d_in, const int* in_sizes, int n_in,
                              void* d_out, int out_size, void* d_ws, size_t ws_size,
                              hipStream_t stream)
{
  float* ws = (float*)d_ws;
  int* flag = (int*)(ws + WS_FLAG);
  float* c    = ws + WS_C;
  float* m    = ws + WS_M;
  float* hnew = ws + WS_HNEW;
  float* zcat = ws + WS_ZCAT;
  float* zwT  = ws + WS_ZWT;
  float* mw4  = ws + WS_MW4;
  ushort* qb16  = (ushort*)(ws + WS_QB16);
  ushort* khb16 = (ushort*)(ws + WS_KHB16);
  ushort* kmb16 = (ushort*)(ws + WS_KMB16);
  ushort* vth16 = (ushort*)(ws + WS_VTH16);
  ushort* vtm16 = (ushort*)(ws + WS_VTM16);
  ushort* wa_hi = (ushort*)(ws + WS_WAHI);
  ushort* wa_lo = (ushort*)(ws + WS_WALO);
  ushort* xt_hi = (ushort*)(ws + WS_XTHI);
  ushort* xt_lo = (ushort*)(ws + WS_XTLO);
  ushort* ht_hi = (ushort*)(ws + WS_HTHI);
  ushort* ht_lo = (ushort*)(ws + WS_HTLO);

  k_probe<<<1, 256, 0, stream>>>((const unsigned int*)d_in[0], flag);
  P18 pk;
  for (int i = 0; i < 18; ++i) pk.p[i] = d_in[2 + i];
  k_wconv<<<dim3(64,18), 256, 0, stream>>>(pk, flag, ws);
  k_init<<<3072, 256, 0, stream>>>(d_in[1], flag, ws);
  k_xt<<<dim3(16,32), 256, 0, stream>>>(d_in[0], flag, ws);
  k_wtrans<<<144, 256, 0, stream>>>(ws);

  for (int t = 0; t < 8; ++t){
    k_conv_mfma<<<dim3(4,16,4), 256, 0, stream>>>(flag, wa_hi, wa_lo, xt_hi, xt_lo,
                                                  ht_hi, ht_lo, ws, c, hnew, t);
    k_proj<<<dim3(64,4), 256, 0, stream>>>(hnew, m, ws, qb16, khb16, kmb16, vth16, vtm16);
    k_fatt<<<dim3(32,4,2), 256, 0, stream>>>(qb16, khb16, kmb16, vth16, vtm16, zcat);
    k_zcomb<<<dim3(128,4), 256, 0, stream>>>(zcat, hnew, ws, zwT, mw4, flag,
                                             m, ht_hi, ht_lo, d_out, t);
  }
  (void)in_sizes; (void)n_in; (void)out_size; (void)ws_size;
}

// Round 7
// 938.846 us; speedup vs baseline: 3.3777x; 1.0148x over previous
//
#include <hip/hip_runtime.h>
#include <hip/hip_bf16.h>

typedef __hip_bfloat16 bf16;
typedef unsigned short ushort;
typedef __attribute__((ext_vector_type(8))) short short8v;   // 8 bf16 = 4 VGPR
typedef __attribute__((ext_vector_type(4))) float float4v;

__device__ __forceinline__ float b2f(bf16 v){ return __bfloat162float(v); }
__device__ __forceinline__ float sigm(float x){ return 1.0f/(1.0f+__expf(-x)); }
__device__ __forceinline__ float tanhc(float x){
  x = fminf(15.0f, fmaxf(-15.0f, x));
  float e = __expf(2.0f*x);
  return (e-1.0f)/(e+1.0f);
}
__device__ __forceinline__ ushort f2bu(float f){
  bf16 h = __float2bfloat16(f); return *reinterpret_cast<ushort*>(&h);
}
__device__ __forceinline__ float bu2f(ushort u){
  return __uint_as_float(((unsigned)u)<<16);
}
__device__ __forceinline__ short8v ldfrag(const ushort* p){
  return *reinterpret_cast<const short8v*>(p);
}

// ---------------------------------------------------------------------------
// ws layout (float offsets)
// ---------------------------------------------------------------------------
#define WS_SMALL   0          // 262144 f32 small weights
#define WS_FLAG    262144
#define WS_H       262208     // h,c,m f32 states (h slot legacy-zeroed)
#define WS_C       524352
#define WS_M       786496
#define WS_HNEW    1048640    // 262144 f32 cell output h_new
#define WS_QB16    1310784    // 65536 f = [b][n][32] bf16 zero-padded
#define WS_KHB16   1376320    // 65536
#define WS_KMB16   1441856    // 65536
#define WS_VTH16   1507392    // 131072 f = [b][c][1024] bf16
#define WS_VTM16   1638464    // 131072
#define WS_ZCAT    1769536    // 524288
#define WS_ZWT     2293824    // 16384
#define WS_MW4     2310208    // 36864
#define WS_WAHI    2347072    // 147456 f (294912 bf16)
#define WS_WALO    2494528    // 147456
#define WS_XTHI    2641984    // 1048576
#define WS_XTLO    3690560    // 1048576
#define WS_HTHI    4739136    // 131072
#define WS_HTLO    4870208    // 131072 -> total 5001280 f = 20 MB
// small-weight offsets inside WS_SMALL
#define O_CB    0
#define O_WCI   256
#define O_WCF   65792
#define O_WCO   131328
#define O_QW    196864
#define O_QB    197888
#define O_KW    197904
#define O_KB    198928
#define O_K2W   198944
#define O_K2B   199968
#define O_VW    199984
#define O_VB    204080
#define O_V2W   204144
#define O_V2B   208240
#define O_ZW    208304
#define O_ZB    224688
#define O_MW    224816
#define O_MB    261680

// ---------------------------------------------------------------------------
// dtype probe (f32 vs bf16 input data)
// ---------------------------------------------------------------------------
__global__ void k_probe(const unsigned int* __restrict__ Xu, int* __restrict__ flag){
  __shared__ int cnt;
  if (threadIdx.x == 0) cnt = 0;
  __syncthreads();
  unsigned int u = Xu[threadIdx.x];
  float f = __uint_as_float((u & 0xffffu) << 16);
  int bad = (fabsf(f) <= 1e4f) ? 0 : 1;
  atomicAdd(&cnt, bad);
  __syncthreads();
  if (threadIdx.x == 0) *flag = (cnt > 16) ? 1 : 0;
}

// ---------------------------------------------------------------------------
// convert the 18 small inputs into f32 copies in ws
// ---------------------------------------------------------------------------
struct P18 { const void* p[18]; };

__global__ __launch_bounds__(256) void k_wconv(P18 pk, const int* __restrict__ flagp,
                                               float* __restrict__ dst){
  const int ns[18]   = {256,65536,65536,65536,1024,16,1024,16,1024,16,
                        4096,64,4096,64,16384,128,36864,192};
  const int offs[18] = {O_CB,O_WCI,O_WCF,O_WCO,O_QW,O_QB,O_KW,O_KB,O_K2W,O_K2B,
                        O_VW,O_VB,O_V2W,O_V2B,O_ZW,O_ZB,O_MW,O_MB};
  int y = blockIdx.y;
  int n = ns[y];
  int flag = *flagp;
  const void* src = pk.p[y];
  for (int i = blockIdx.x*256 + threadIdx.x; i < n; i += gridDim.x*256){
    float v = flag ? ((const float*)src)[i] : b2f(((const bf16*)src)[i]);
    dst[offs[y] + i] = v;
  }
}

// transpose z_w into [k][r]; pack m_w into mw4[(k4*192 + r)*4 + q]
__global__ __launch_bounds__(256) void k_wtrans(float* __restrict__ ws){
  int i = blockIdx.x*256 + threadIdx.x;
  if (i < 16384){
    int k = i >> 7, r = i & 127;
    ws[WS_ZWT + k*128 + r] = ws[O_ZW + r*128 + k];
  }
  if (i < 36864){
    int q = i & 3; int rest = i >> 2; int r = rest % 192; int k4 = rest / 192;
    ws[WS_MW4 + i] = ws[O_MW + r*192 + k4*4 + q];
  }
}

// ---------------------------------------------------------------------------
// init: zero h,c,m + hT; build MFMA weight layout wA (hi/lo)
// ---------------------------------------------------------------------------
__global__ __launch_bounds__(256) void k_init(const void* __restrict__ conv_w,
                                              const int* __restrict__ flagp,
                                              float* __restrict__ ws){
  int i = blockIdx.x*256 + threadIdx.x;
  int flag = *flagp;
  if (i < 786432) ws[WS_H + i] = 0.0f;
  if (i < 294912){
    int ci = i & 127;
    int j = i >> 7;
    int mm = j & 255, p = j >> 8;
    int cc = mm >> 2, g = mm & 3;
    int si = ((g*64 + cc)*128 + ci)*9 + p;
    ushort* wah = (ushort*)(ws + WS_WAHI);
    ushort* wal = (ushort*)(ws + WS_WALO);
    if (flag){
      float f = ((const float*)conv_w)[si];
      ushort hi = f2bu(f);
      wah[i] = hi;
      wal[i] = f2bu(f - bu2f(hi));
    } else {
      wah[i] = ((const ushort*)conv_w)[si];
    }
  }
  if (i < 131072){
    ((unsigned*)(ws + WS_HTHI))[i] = 0u;
    ((unsigned*)(ws + WS_HTLO))[i] = 0u;
  }
}

// ---------------------------------------------------------------------------
// X transpose: XT[b][t][px][ci]
// ---------------------------------------------------------------------------
__global__ __launch_bounds__(256) void k_xt(const void* __restrict__ Xraw,
                                            const int* __restrict__ flagp,
                                            float* __restrict__ ws){
  __shared__ ushort hi_s[64][66];
  __shared__ ushort lo_s[64][66];
  int pt = blockIdx.x, s = blockIdx.y;
  int b = s >> 3, t = s & 7;
  int flag = *flagp;
  int tid = threadIdx.x;
  for (int k = 0; k < 16; ++k){
    int idx = tid + k*256;
    int ci = idx >> 6, pxl = idx & 63;
    size_t si = ((size_t)(b*64 + ci)*8 + t)*1024 + pt*64 + pxl;
    if (flag){
      float f = ((const float*)Xraw)[si];
      ushort h = f2bu(f);
      hi_s[pxl][ci] = h;
      lo_s[pxl][ci] = f2bu(f - bu2f(h));
    } else {
      hi_s[pxl][ci] = ((const ushort*)Xraw)[si];
    }
  }
  __syncthreads();
  ushort* xh = (ushort*)(ws + WS_XTHI) + ((size_t)s*1024 + pt*64)*64;
  ushort* xl = (ushort*)(ws + WS_XTLO) + ((size_t)s*1024 + pt*64)*64;
  for (int k = 0; k < 16; ++k){
    int idx = tid + k*256;
    int pxl = idx >> 6, ci = idx & 63;
    xh[pxl*64 + ci] = hi_s[pxl][ci];
    if (flag) xl[pxl*64 + ci] = lo_s[pxl][ci];
  }
}

// ---------------------------------------------------------------------------
// conv 3x3 + peephole LSTM via MFMA implicit GEMM (9 shifted 1x1 passes).
// grid (16 nblk, 8 mt, 4 b) = 512 blocks (2/CU, 2 waves/SIMD), block 256.
// wave: 2 m-frags (rows mt*32 + mf*16), 16 px (n0 = nblk*64 + wave*16).
// nblk fastest-varying: consecutive blocks share the weight slice in L2.
// ---------------------------------------------------------------------------
__global__ __launch_bounds__(256) void k_conv_mfma(
  const int* __restrict__ flagp,
  const ushort* __restrict__ wa_hi, const ushort* __restrict__ wa_lo,
  const ushort* __restrict__ xt_hi, const ushort* __restrict__ xt_lo,
  const ushort* __restrict__ ht_hi, const ushort* __restrict__ ht_lo,
  const float* __restrict__ smalls, float* __restrict__ cst,
  float* __restrict__ hnew, int t)
{
  int nblk = blockIdx.x, mt = blockIdx.y, b = blockIdx.z;
  int tid = threadIdx.x;
  int wave = tid >> 6, lane = tid & 63;
  int lr = lane & 15, lk = lane >> 4;
  int flag = *flagp;
  int n0 = nblk*64 + wave*16;
  int px = n0 + lr, y = px >> 5, x = px & 31;
  int m0 = mt*32;
  const ushort* xb  = xt_hi + ((size_t)(b*8 + t))*65536;
  const ushort* xlb = xt_lo + ((size_t)(b*8 + t))*65536;
  const ushort* hb  = ht_hi + (size_t)b*65536;
  const ushort* hlb = ht_lo + (size_t)b*65536;
  const short8v ZF = {0,0,0,0,0,0,0,0};

  float4v acc[2];
  acc[0] = (float4v){0.f,0.f,0.f,0.f};
  acc[1] = (float4v){0.f,0.f,0.f,0.f};

  #pragma unroll 1
  for (int p = 0; p < 9; ++p){
    int dy = p/3 - 1, dx = p%3 - 1;
    int py = y + dy, xx = x + dx;
    bool valid = (py >= 0) & (py < 32) & (xx >= 0) & (xx < 32);
    int pin = valid ? (py*32 + xx) : 0;
    int boff = pin*64 + lk*8;

    short8v AX[2][2], AH[2][2];
    #pragma unroll
    for (int mf=0; mf<2; ++mf){
      const ushort* ar = wa_hi + (size_t)(p*256 + m0 + mf*16 + lr)*128 + lk*8;
      AX[mf][0] = ldfrag(ar);      AX[mf][1] = ldfrag(ar + 32);
      AH[mf][0] = ldfrag(ar + 64); AH[mf][1] = ldfrag(ar + 96);
    }
    short8v BX[2], BH[2], BL[2];
    BX[0] = ldfrag(xb + boff);   BX[1] = ldfrag(xb + boff + 32);
    BH[0] = ldfrag(hb + boff);   BH[1] = ldfrag(hb + boff + 32);
    BL[0] = ldfrag(hlb + boff);  BL[1] = ldfrag(hlb + boff + 32);
    if (!valid){
      BX[0]=ZF; BX[1]=ZF; BH[0]=ZF; BH[1]=ZF; BL[0]=ZF; BL[1]=ZF;
    }
    #pragma unroll
    for (int kh=0; kh<2; ++kh){
      #pragma unroll
      for (int mf=0; mf<2; ++mf){
        acc[mf] = __builtin_amdgcn_mfma_f32_16x16x32_bf16(AX[mf][kh], BX[kh], acc[mf], 0,0,0);
        acc[mf] = __builtin_amdgcn_mfma_f32_16x16x32_bf16(AH[mf][kh], BH[kh], acc[mf], 0,0,0);
        acc[mf] = __builtin_amdgcn_mfma_f32_16x16x32_bf16(AH[mf][kh], BL[kh], acc[mf], 0,0,0);
      }
    }
    if (flag){
      short8v AXl[2][2], AHl[2][2];
      #pragma unroll
      for (int mf=0; mf<2; ++mf){
        const ushort* ar = wa_lo + (size_t)(p*256 + m0 + mf*16 + lr)*128 + lk*8;
        AXl[mf][0] = ldfrag(ar);      AXl[mf][1] = ldfrag(ar + 32);
        AHl[mf][0] = ldfrag(ar + 64); AHl[mf][1] = ldfrag(ar + 96);
      }
      short8v BXl[2];
      BXl[0] = ldfrag(xlb + boff); BXl[1] = ldfrag(xlb + boff + 32);
      if (!valid){ BXl[0]=ZF; BXl[1]=ZF; }
      #pragma unroll
      for (int kh=0; kh<2; ++kh){
        #pragma unroll
        for (int mf=0; mf<2; ++mf){
          acc[mf] = __builtin_amdgcn_mfma_f32_16x16x32_bf16(AXl[mf][kh], BX[kh],  acc[mf], 0,0,0);
          acc[mf] = __builtin_amdgcn_mfma_f32_16x16x32_bf16(AX[mf][kh],  BXl[kh], acc[mf], 0,0,0);
          acc[mf] = __builtin_amdgcn_mfma_f32_16x16x32_bf16(AHl[mf][kh], BH[kh],  acc[mf], 0,0,0);
        }
      }
    }
  }

  #pragma unroll
  for (int mf=0; mf<2; ++mf){
    int cc = mt*8 + mf*4 + lk;
    int wi = cc*1024 + px;
    size_t sidx = ((size_t)(b*64 + cc))*1024 + px;
    float cprev = cst[sidx];
    float ic = acc[mf][0] + smalls[O_CB + cc];
    float fc = acc[mf][1] + smalls[O_CB + 64 + cc];
    float gc = acc[mf][2] + smalls[O_CB + 128 + cc];
    float oc = acc[mf][3] + smalls[O_CB + 192 + cc];
    float ig = sigm(ic + smalls[O_WCI + wi]*cprev);
    float fg = sigm(fc + smalls[O_WCF + wi]*cprev);
    float cnew = fg*cprev + ig*tanhc(gc);
    float og = sigm(oc + smalls[O_WCO + wi]*cnew);
    cst[sidx]  = cnew;
    hnew[sidx] = og*tanhc(cnew);
  }
}

// ---------------------------------------------------------------------------
// 1x1 projections -> bf16 MFMA-ready buffers.
// grid (128 ntiles of 8, 4 b) = 512 blocks (2/CU), block 256
// ---------------------------------------------------------------------------
__global__ __launch_bounds__(256) void k_proj(
  const float* __restrict__ hnew, const float* __restrict__ mst,
  const float* __restrict__ smalls,
  ushort* __restrict__ qb16, ushort* __restrict__ khb16, ushort* __restrict__ kmb16,
  ushort* __restrict__ vth16, ushort* __restrict__ vtm16)
{
  __shared__ float hs[64*9];
  __shared__ float ms[64*9];
  int b = blockIdx.y, n0 = blockIdx.x*8;
  int tid = threadIdx.x, nl = tid&7, rg = tid>>3;
  for (int idx = tid; idx < 512; idx += 256){
    int nn = idx & 7, ch = idx >> 3;
    hs[ch*9+nn] = hnew[((size_t)b*64+ch)*1024 + n0 + nn];
    ms[ch*9+nn] = mst [((size_t)b*64+ch)*1024 + n0 + nn];
  }
  __syncthreads();
  int n = n0 + nl;
  for (int j = 0; j < 6; ++j){
    int r = rg + 32*j;
    if (r >= 176) break;
    const float* src; const float* wrow; float bias;
    int mode, rr;
    if (r < 16)      { mode=0; rr=r;     src = hs; wrow = smalls+O_QW  + rr*64; bias = smalls[O_QB+rr]; }
    else if (r < 32) { mode=1; rr=r-16;  src = hs; wrow = smalls+O_KW  + rr*64; bias = smalls[O_KB+rr]; }
    else if (r < 48) { mode=2; rr=r-32;  src = ms; wrow = smalls+O_K2W + rr*64; bias = smalls[O_K2B+rr]; }
    else if (r < 112){ mode=3; rr=r-48;  src = hs; wrow = smalls+O_VW  + rr*64; bias = smalls[O_VB+rr]; }
    else             { mode=4; rr=r-112; src = ms; wrow = smalls+O_V2W + rr*64; bias = smalls[O_V2B+rr]; }
    float acc = bias;
    #pragma unroll
    for (int c4 = 0; c4 < 16; ++c4){
      float4 w4 = *reinterpret_cast<const float4*>(wrow + c4*4);
      acc += w4.x*src[(c4*4+0)*9+nl] + w4.y*src[(c4*4+1)*9+nl]
           + w4.z*src[(c4*4+2)*9+nl] + w4.w*src[(c4*4+3)*9+nl];
    }
    ushort v = f2bu(acc);
    if (mode <= 2){
      ushort* base = (mode==0) ? qb16 : (mode==1) ? khb16 : kmb16;
      size_t o = ((size_t)b*1024 + n)*32;
      base[o + rr] = v;
      base[o + 16 + rr] = 0;
    } else {
      ushort* base = (mode==3) ? vth16 : vtm16;
      base[((size_t)b*64 + rr)*1024 + n] = v;
    }
  }
}

// ---------------------------------------------------------------------------
// MFMA flash attention. grid (64 ntiles of 16, 4 b, 2 br) = 512 blocks (2/CU),
// block 256 = 4 waves. scores: A=K[m][32pad], B=Q[n][32pad] (regs); exp->bf16
// -> LDS es[n][m] (B-frag layout). PV: A=VT[c][1024], B=P from LDS.
// ---------------------------------------------------------------------------
__global__ __launch_bounds__(256) void k_fatt(
  const ushort* __restrict__ qb16, const ushort* __restrict__ khb16,
  const ushort* __restrict__ kmb16, const ushort* __restrict__ vth16,
  const ushort* __restrict__ vtm16, float* __restrict__ zcat)
{
  __shared__ ushort es[16*272];
  __shared__ float rs_s[4][16];
  int n0 = blockIdx.x*16, b = blockIdx.y, br = blockIdx.z;
  const ushort* kb = (br ? kmb16 : khb16) + (size_t)b*32768;
  const ushort* vt = (br ? vtm16 : vth16) + (size_t)b*65536;
  const ushort* qp = qb16 + (size_t)b*32768;
  int tid = threadIdx.x;
  int w = tid >> 6, lane = tid & 63, lr = lane & 15, lk = lane >> 4;
  const float4v Z4 = {0.f,0.f,0.f,0.f};

  short8v qf = ldfrag(qp + (size_t)(n0 + lr)*32 + lk*8);

  float4v acc[2];
  acc[0]=Z4; acc[1]=Z4;
  float rsum = 0.f;

  #pragma unroll 1
  for (int mc = 0; mc < 4; ++mc){
    int mbase = mc*256 + w*64;
    #pragma unroll
    for (int tau = 0; tau < 4; ++tau){
      short8v af = ldfrag(kb + (size_t)(mbase + tau*16 + lr)*32 + lk*8);
      float4v d = __builtin_amdgcn_mfma_f32_16x16x32_bf16(af, qf, Z4, 0,0,0);
      ushort u0 = f2bu(__expf(fminf(d[0], 60.f)));
      ushort u1 = f2bu(__expf(fminf(d[1], 60.f)));
      ushort u2 = f2bu(__expf(fminf(d[2], 60.f)));
      ushort u3 = f2bu(__expf(fminf(d[3], 60.f)));
      rsum += (bu2f(u0) + bu2f(u1)) + (bu2f(u2) + bu2f(u3));
      unsigned lo = (unsigned)u0 | ((unsigned)u1 << 16);
      unsigned hi = (unsigned)u2 | ((unsigned)u3 << 16);
      *reinterpret_cast<uint2*>(&es[lr*272 + w*64 + tau*16 + lk*4]) = make_uint2(lo, hi);
    }
    __syncthreads();
    #pragma unroll
    for (int ks = 0; ks < 8; ++ks){
      short8v av = ldfrag(vt + (size_t)(w*16 + lr)*1024 + mc*256 + ks*32 + lk*8);
      short8v bv = ldfrag(&es[lr*272 + ks*32 + lk*8]);
      acc[ks & 1] = __builtin_amdgcn_mfma_f32_16x16x32_bf16(av, bv, acc[ks & 1], 0,0,0);
    }
    __syncthreads();
  }

  {
    float r = rsum;
    r += __shfl_xor(r, 16);
    r += __shfl_xor(r, 32);
    if (lane < 16) rs_s[w][lr] = r;
  }
  __syncthreads();
  {
    float rinv = 1.0f / (rs_s[0][lr] + rs_s[1][lr] + rs_s[2][lr] + rs_s[3][lr]);
    #pragma unroll
    for (int r = 0; r < 4; ++r){
      int c = w*16 + lk*4 + r;
      zcat[((size_t)(b*128 + br*64 + c))*1024 + n0 + lr] = (acc[0][r] + acc[1][r])*rinv;
    }
  }
}

// ---------------------------------------------------------------------------
// zcomb: zt = zwT^T@zcat+z_b; comb = mw4@[zt;hnew]+m_b; gate; h_out
// writes m state, hT_hi/lo bf16, and d_out
// ---------------------------------------------------------------------------
__global__ __launch_bounds__(256) void k_zcomb(
  const float* __restrict__ zcat, const float* __restrict__ hnew,
  const float* __restrict__ smalls, const float* __restrict__ zwT,
  const float* __restrict__ mw4, const int* __restrict__ flagp,
  float* __restrict__ mst, ushort* __restrict__ hth, ushort* __restrict__ htl,
  void* __restrict__ outraw, int t)
{
  __shared__ float zin[128*9];
  __shared__ float hl [64*9];
  __shared__ float ml [64*9];
  __shared__ float zt_s[8*132];
  __shared__ float ho_s[64*9];
  __shared__ float mn_s[64*9];
  int n0 = blockIdx.x*8, b = blockIdx.y;
  int tid = threadIdx.x;
  int px = tid >> 5, lr = tid & 31;
  int flag = *flagp;
  for (int idx = tid; idx < 1024; idx += 256){
    int ch = idx >> 3, pp = idx & 7;
    zin[ch*9+pp] = zcat[((size_t)b*128 + ch)*1024 + n0 + pp];
  }
  for (int idx = tid; idx < 512; idx += 256){
    int ch = idx >> 3, pp = idx & 7;
    hl[ch*9+pp] = hnew[((size_t)b*64 + ch)*1024 + n0 + pp];
    ml[ch*9+pp] = mst [((size_t)b*64 + ch)*1024 + n0 + pp];
  }
  __syncthreads();
  {
    float4 a4 = *reinterpret_cast<const float4*>(&smalls[O_ZB + lr*4]);
    float acc0=a4.x, acc1=a4.y, acc2=a4.z, acc3=a4.w;
    #pragma unroll 4
    for (int k = 0; k < 128; ++k){
      float zv = zin[k*9 + px];
      float4 w4 = *reinterpret_cast<const float4*>(&zwT[k*128 + lr*4]);
      acc0 += w4.x*zv; acc1 += w4.y*zv; acc2 += w4.z*zv; acc3 += w4.w*zv;
    }
    *reinterpret_cast<float4*>(&zt_s[px*132 + lr*4]) = make_float4(acc0,acc1,acc2,acc3);
  }
  __syncthreads();
  {
    float acc6[6];
    #pragma unroll
    for (int i=0;i<6;++i) acc6[i] = smalls[O_MB + lr + 32*i];
    #pragma unroll 2
    for (int k4 = 0; k4 < 32; ++k4){
      float4 xv = *reinterpret_cast<const float4*>(&zt_s[px*132 + k4*4]);
      const float* wb = mw4 + (size_t)(k4*192)*4;
      #pragma unroll
      for (int i=0;i<6;++i){
        float4 w = *reinterpret_cast<const float4*>(&wb[(lr + 32*i)*4]);
        acc6[i] += w.x*xv.x + w.y*xv.y + w.z*xv.z + w.w*xv.w;
      }
    }
    #pragma unroll 2
    for (int k4 = 32; k4 < 48; ++k4){
      int ch = (k4-32)*4;
      float4 xv = make_float4(hl[ch*9+px], hl[(ch+1)*9+px], hl[(ch+2)*9+px], hl[(ch+3)*9+px]);
      const float* wb = mw4 + (size_t)(k4*192)*4;
      #pragma unroll
      for (int i=0;i<6;++i){
        float4 w = *reinterpret_cast<const float4*>(&wb[(lr + 32*i)*4]);
        acc6[i] += w.x*xv.x + w.y*xv.y + w.z*xv.z + w.w*xv.w;
      }
    }
    #pragma unroll
    for (int j=0;j<2;++j){
      int ch = lr + 32*j;
      float mold = ml[ch*9 + px];
      float gi = sigm(acc6[4+j]);
      float mnew = (1.0f-gi)*mold + gi*tanhc(acc6[2+j]);
      float ho = sigm(acc6[j])*mnew;
      ho_s[ch*9+px] = ho;
      mn_s[ch*9+px] = mnew;
    }
  }
  __syncthreads();
  for (int idx = tid; idx < 512; idx += 256){
    int ch = idx >> 3, pp = idx & 7;
    int n = n0 + pp;
    size_t gidx = ((size_t)b*64 + ch)*1024 + n;
    mst[gidx] = mn_s[ch*9+pp];
    float ho = ho_s[ch*9+pp];
    size_t tix = ((size_t)b*1024 + n)*64 + ch;
    ushort hb_ = f2bu(ho);
    hth[tix] = hb_;
    htl[tix] = f2bu(ho - bu2f(hb_));
    size_t oidx = ((size_t)(b*64+ch)*8 + t)*1024 + n;
    if (flag) ((float*)outraw)[oidx] = ho;
    else      ((bf16*)outraw)[oidx] = __float2bfloat16(ho);
  }
}

extern "C" void kernel_launch(void* const* d_in, const int* in_sizes, int n_in,
                              void* d_out, int out_size, void* d_ws, size_t ws_size,
                              hipStream_t stream)
{
  float* ws = (float*)d_ws;
  int* flag = (int*)(ws + WS_FLAG);
  float* c    = ws + WS_C;
  float* m    = ws + WS_M;
  float* hnew = ws + WS_HNEW;
  float* zcat = ws + WS_ZCAT;
  float* zwT  = ws + WS_ZWT;
  float* mw4  = ws + WS_MW4;
  ushort* qb16  = (ushort*)(ws + WS_QB16);
  ushort* khb16 = (ushort*)(ws + WS_KHB16);
  ushort* kmb16 = (ushort*)(ws + WS_KMB16);
  ushort* vth16 = (ushort*)(ws + WS_VTH16);
  ushort* vtm16 = (ushort*)(ws + WS_VTM16);
  ushort* wa_hi = (ushort*)(ws + WS_WAHI);
  ushort* wa_lo = (ushort*)(ws + WS_WALO);
  ushort* xt_hi = (ushort*)(ws + WS_XTHI);
  ushort* xt_lo = (ushort*)(ws + WS_XTLO);
  ushort* ht_hi = (ushort*)(ws + WS_HTHI);
  ushort* ht_lo = (ushort*)(ws + WS_HTLO);

  k_probe<<<1, 256, 0, stream>>>((const unsigned int*)d_in[0], flag);
  P18 pk;
  for (int i = 0; i < 18; ++i) pk.p[i] = d_in[2 + i];
  k_wconv<<<dim3(64,18), 256, 0, stream>>>(pk, flag, ws);
  k_init<<<3072, 256, 0, stream>>>(d_in[1], flag, ws);
  k_xt<<<dim3(16,32), 256, 0, stream>>>(d_in[0], flag, ws);
  k_wtrans<<<144, 256, 0, stream>>>(ws);

  for (int t = 0; t < 8; ++t){
    k_conv_mfma<<<dim3(16,8,4), 256, 0, stream>>>(flag, wa_hi, wa_lo, xt_hi, xt_lo,
                                                  ht_hi, ht_lo, ws, c, hnew, t);
    k_proj<<<dim3(128,4), 256, 0, stream>>>(hnew, m, ws, qb16, khb16, kmb16, vth16, vtm16);
    k_fatt<<<dim3(64,4,2), 256, 0, stream>>>(qb16, khb16, kmb16, vth16, vtm16, zcat);
    k_zcomb<<<dim3(128,4), 256, 0, stream>>>(zcat, hnew, ws, zwT, mw4, flag,
                                             m, ht_hi, ht_lo, d_out, t);
  }
  (void)in_sizes; (void)n_in; (void)out_size; (void)ws_size;
}

// Round 8
// 843.491 us; speedup vs baseline: 3.7595x; 1.1130x over previous
//
#include <hip/hip_runtime.h>
#include <hip/hip_bf16.h>

typedef __hip_bfloat16 bf16;
typedef unsigned short ushort;
typedef __attribute__((ext_vector_type(8))) short short8v;   // 8 bf16 = 4 VGPR
typedef __attribute__((ext_vector_type(4))) float float4v;

__device__ __forceinline__ float b2f(bf16 v){ return __bfloat162float(v); }
__device__ __forceinline__ float sigm(float x){ return 1.0f/(1.0f+__expf(-x)); }
__device__ __forceinline__ float tanhc(float x){
  x = fminf(15.0f, fmaxf(-15.0f, x));
  float e = __expf(2.0f*x);
  return (e-1.0f)/(e+1.0f);
}
__device__ __forceinline__ ushort f2bu(float f){
  bf16 h = __float2bfloat16(f); return *reinterpret_cast<ushort*>(&h);
}
__device__ __forceinline__ float bu2f(ushort u){
  return __uint_as_float(((unsigned)u)<<16);
}
__device__ __forceinline__ short8v ldfrag(const ushort* p){
  return *reinterpret_cast<const short8v*>(p);
}

// ---------------------------------------------------------------------------
// ws layout (float offsets)
// ---------------------------------------------------------------------------
#define WS_SMALL   0          // 262144 f32 small weights
#define WS_FLAG    262144
#define WS_H       262208     // h,c,m f32 states (h slot legacy-zeroed)
#define WS_C       524352
#define WS_M       786496
#define WS_HNEW    1048640    // 262144 f32 cell output h_new
#define WS_QB16    1310784    // 65536 f = [b][n][32] bf16 zero-padded
#define WS_KHB16   1376320    // 65536
#define WS_KMB16   1441856    // 65536
#define WS_VTH16   1507392    // 131072 f = [b][c][1024] bf16
#define WS_VTM16   1638464    // 131072
#define WS_ZCAT    1769536    // 524288
#define WS_ZWT     2293824    // 16384
#define WS_MW4     2310208    // 36864
#define WS_WAHI    2347072    // 147456 f (294912 bf16)
#define WS_WALO    2494528    // 147456
#define WS_XTHI    2641984    // 1048576
#define WS_XTLO    3690560    // 1048576
#define WS_HTHI    4739136    // 131072
#define WS_HTLO    4870208    // 131072 -> total 5001280 f = 20 MB
// small-weight offsets inside WS_SMALL
#define O_CB    0
#define O_WCI   256
#define O_WCF   65792
#define O_WCO   131328
#define O_QW    196864
#define O_QB    197888
#define O_KW    197904
#define O_KB    198928
#define O_K2W   198944
#define O_K2B   199968
#define O_VW    199984
#define O_VB    204080
#define O_V2W   204144
#define O_V2B   208240
#define O_ZW    208304
#define O_ZB    224688
#define O_MW    224816
#define O_MB    261680

// ---------------------------------------------------------------------------
// dtype probe (f32 vs bf16 input data)
// ---------------------------------------------------------------------------
__global__ void k_probe(const unsigned int* __restrict__ Xu, int* __restrict__ flag){
  __shared__ int cnt;
  if (threadIdx.x == 0) cnt = 0;
  __syncthreads();
  unsigned int u = Xu[threadIdx.x];
  float f = __uint_as_float((u & 0xffffu) << 16);
  int bad = (fabsf(f) <= 1e4f) ? 0 : 1;
  atomicAdd(&cnt, bad);
  __syncthreads();
  if (threadIdx.x == 0) *flag = (cnt > 16) ? 1 : 0;
}

// ---------------------------------------------------------------------------
// convert the 18 small inputs into f32 copies in ws
// ---------------------------------------------------------------------------
struct P18 { const void* p[18]; };

__global__ __launch_bounds__(256) void k_wconv(P18 pk, const int* __restrict__ flagp,
                                               float* __restrict__ dst){
  const int ns[18]   = {256,65536,65536,65536,1024,16,1024,16,1024,16,
                        4096,64,4096,64,16384,128,36864,192};
  const int offs[18] = {O_CB,O_WCI,O_WCF,O_WCO,O_QW,O_QB,O_KW,O_KB,O_K2W,O_K2B,
                        O_VW,O_VB,O_V2W,O_V2B,O_ZW,O_ZB,O_MW,O_MB};
  int y = blockIdx.y;
  int n = ns[y];
  int flag = *flagp;
  const void* src = pk.p[y];
  for (int i = blockIdx.x*256 + threadIdx.x; i < n; i += gridDim.x*256){
    float v = flag ? ((const float*)src)[i] : b2f(((const bf16*)src)[i]);
    dst[offs[y] + i] = v;
  }
}

// transpose z_w into [k][r]; pack m_w into mw4[(k4*192 + r)*4 + q]
__global__ __launch_bounds__(256) void k_wtrans(float* __restrict__ ws){
  int i = blockIdx.x*256 + threadIdx.x;
  if (i < 16384){
    int k = i >> 7, r = i & 127;
    ws[WS_ZWT + k*128 + r] = ws[O_ZW + r*128 + k];
  }
  if (i < 36864){
    int q = i & 3; int rest = i >> 2; int r = rest % 192; int k4 = rest / 192;
    ws[WS_MW4 + i] = ws[O_MW + r*192 + k4*4 + q];
  }
}

// ---------------------------------------------------------------------------
// init: zero h,c,m + hT; build MFMA weight layout wA (hi/lo)
// ---------------------------------------------------------------------------
__global__ __launch_bounds__(256) void k_init(const void* __restrict__ conv_w,
                                              const int* __restrict__ flagp,
                                              float* __restrict__ ws){
  int i = blockIdx.x*256 + threadIdx.x;
  int flag = *flagp;
  if (i < 786432) ws[WS_H + i] = 0.0f;
  if (i < 294912){
    int ci = i & 127;
    int j = i >> 7;
    int mm = j & 255, p = j >> 8;
    int cc = mm >> 2, g = mm & 3;
    int si = ((g*64 + cc)*128 + ci)*9 + p;
    ushort* wah = (ushort*)(ws + WS_WAHI);
    ushort* wal = (ushort*)(ws + WS_WALO);
    if (flag){
      float f = ((const float*)conv_w)[si];
      ushort hi = f2bu(f);
      wah[i] = hi;
      wal[i] = f2bu(f - bu2f(hi));
    } else {
      wah[i] = ((const ushort*)conv_w)[si];
    }
  }
  if (i < 131072){
    ((unsigned*)(ws + WS_HTHI))[i] = 0u;
    ((unsigned*)(ws + WS_HTLO))[i] = 0u;
  }
}

// ---------------------------------------------------------------------------
// X transpose: XT[b][t][px][ci]
// ---------------------------------------------------------------------------
__global__ __launch_bounds__(256) void k_xt(const void* __restrict__ Xraw,
                                            const int* __restrict__ flagp,
                                            float* __restrict__ ws){
  __shared__ ushort hi_s[64][66];
  __shared__ ushort lo_s[64][66];
  int pt = blockIdx.x, s = blockIdx.y;
  int b = s >> 3, t = s & 7;
  int flag = *flagp;
  int tid = threadIdx.x;
  for (int k = 0; k < 16; ++k){
    int idx = tid + k*256;
    int ci = idx >> 6, pxl = idx & 63;
    size_t si = ((size_t)(b*64 + ci)*8 + t)*1024 + pt*64 + pxl;
    if (flag){
      float f = ((const float*)Xraw)[si];
      ushort h = f2bu(f);
      hi_s[pxl][ci] = h;
      lo_s[pxl][ci] = f2bu(f - bu2f(h));
    } else {
      hi_s[pxl][ci] = ((const ushort*)Xraw)[si];
    }
  }
  __syncthreads();
  ushort* xh = (ushort*)(ws + WS_XTHI) + ((size_t)s*1024 + pt*64)*64;
  ushort* xl = (ushort*)(ws + WS_XTLO) + ((size_t)s*1024 + pt*64)*64;
  for (int k = 0; k < 16; ++k){
    int idx = tid + k*256;
    int pxl = idx >> 6, ci = idx & 63;
    xh[pxl*64 + ci] = hi_s[pxl][ci];
    if (flag) xl[pxl*64 + ci] = lo_s[pxl][ci];
  }
}

// ---------------------------------------------------------------------------
// conv 3x3 + peephole LSTM via MFMA implicit GEMM.
// grid (64 ntiles of 16px, 4 b) = 256 blocks, block 512 = 8 waves (2 blk/CU,
// 4 waves/SIMD). Wave w owns m rows [w*32, w*32+32) (2 m-frags); all waves
// share one 16-px n-tile whose 3x18-px halo (X hi, h hi, h lo, [x lo]) is
// staged once in LDS (zero-padded edges -> no per-lane predication).
// LDS slot stride 264 ushort = 132 words; 132%32=4 -> 2 lanes/bank per
// 16-lane phase (free). Epilogue: cc = w*8+mf*4+lk, gate = reg.
// ---------------------------------------------------------------------------
__global__ __launch_bounds__(512, 4) void k_conv_mfma(
  const int* __restrict__ flagp,
  const ushort* __restrict__ wa_hi, const ushort* __restrict__ wa_lo,
  const ushort* __restrict__ xt_hi, const ushort* __restrict__ xt_lo,
  const ushort* __restrict__ ht_hi, const ushort* __restrict__ ht_lo,
  const float* __restrict__ smalls, float* __restrict__ cst,
  float* __restrict__ hnew, int t)
{
  __shared__ ushort bsm[54*264];
  int nt = blockIdx.x, b = blockIdx.y;
  int tid = threadIdx.x;
  int flag = *flagp;
  int ytile = nt >> 1, x0 = (nt & 1) * 16;

  const ushort* xb  = xt_hi + ((size_t)(b*8 + t))*65536;
  const ushort* xlb = xt_lo + ((size_t)(b*8 + t))*65536;
  const ushort* hb  = ht_hi + (size_t)b*65536;
  const ushort* hlb = ht_lo + (size_t)b*65536;

  // stage halo: 54 slots (3 rows x 18 x) x 32 chunks of 8 ushort
  const uint4 Z16 = make_uint4(0,0,0,0);
  for (int idx = tid; idx < 1728; idx += 512){
    int slot = idx >> 5, c = idx & 31;
    int rr = slot / 18, xi = slot - rr*18;
    int gy = ytile - 1 + rr, gx = x0 - 1 + xi;
    bool valid = (gy >= 0) & (gy < 32) & (gx >= 0) & (gx < 32);
    int px = gy*32 + gx;
    uint4 v = Z16;
    if (valid){
      if (c < 8)       v = *reinterpret_cast<const uint4*>(xb  + (size_t)px*64 + c*8);
      else if (c < 16) v = *reinterpret_cast<const uint4*>(hb  + (size_t)px*64 + (c-8)*8);
      else if (c < 24) v = *reinterpret_cast<const uint4*>(hlb + (size_t)px*64 + (c-16)*8);
      else if (flag)   v = *reinterpret_cast<const uint4*>(xlb + (size_t)px*64 + (c-24)*8);
    }
    *reinterpret_cast<uint4*>(&bsm[slot*264 + c*8]) = v;
  }
  __syncthreads();

  int w = tid >> 6, lane = tid & 63, lr = lane & 15, lk = lane >> 4;
  int m0 = w * 32;
  int px = nt*16 + lr;

  float4v acc[2];
  acc[0] = (float4v){0.f,0.f,0.f,0.f};
  acc[1] = (float4v){0.f,0.f,0.f,0.f};

  #pragma unroll
  for (int p = 0; p < 9; ++p){
    int pinl = (p/3)*18 + lr + (p%3);
    const ushort* bl = &bsm[pinl*264 + lk*8];
    short8v BX0 = ldfrag(bl),      BX1 = ldfrag(bl+32);
    short8v BH0 = ldfrag(bl+64),   BH1 = ldfrag(bl+96);
    short8v BL0 = ldfrag(bl+128),  BL1 = ldfrag(bl+160);
    #pragma unroll
    for (int mf = 0; mf < 2; ++mf){
      const ushort* ar = wa_hi + (size_t)(p*256 + m0 + mf*16 + lr)*128 + lk*8;
      short8v AX0 = ldfrag(ar),    AX1 = ldfrag(ar+32);
      short8v AH0 = ldfrag(ar+64), AH1 = ldfrag(ar+96);
      acc[mf] = __builtin_amdgcn_mfma_f32_16x16x32_bf16(AX0, BX0, acc[mf], 0,0,0);
      acc[mf] = __builtin_amdgcn_mfma_f32_16x16x32_bf16(AX1, BX1, acc[mf], 0,0,0);
      acc[mf] = __builtin_amdgcn_mfma_f32_16x16x32_bf16(AH0, BH0, acc[mf], 0,0,0);
      acc[mf] = __builtin_amdgcn_mfma_f32_16x16x32_bf16(AH1, BH1, acc[mf], 0,0,0);
      acc[mf] = __builtin_amdgcn_mfma_f32_16x16x32_bf16(AH0, BL0, acc[mf], 0,0,0);
      acc[mf] = __builtin_amdgcn_mfma_f32_16x16x32_bf16(AH1, BL1, acc[mf], 0,0,0);
      if (flag){
        short8v BXl0 = ldfrag(bl+192), BXl1 = ldfrag(bl+224);
        const ushort* arl = wa_lo + (size_t)(p*256 + m0 + mf*16 + lr)*128 + lk*8;
        short8v AXl0 = ldfrag(arl),    AXl1 = ldfrag(arl+32);
        short8v AHl0 = ldfrag(arl+64), AHl1 = ldfrag(arl+96);
        acc[mf] = __builtin_amdgcn_mfma_f32_16x16x32_bf16(AX0,  BXl0, acc[mf], 0,0,0);
        acc[mf] = __builtin_amdgcn_mfma_f32_16x16x32_bf16(AX1,  BXl1, acc[mf], 0,0,0);
        acc[mf] = __builtin_amdgcn_mfma_f32_16x16x32_bf16(AXl0, BX0,  acc[mf], 0,0,0);
        acc[mf] = __builtin_amdgcn_mfma_f32_16x16x32_bf16(AXl1, BX1,  acc[mf], 0,0,0);
        acc[mf] = __builtin_amdgcn_mfma_f32_16x16x32_bf16(AHl0, BH0,  acc[mf], 0,0,0);
        acc[mf] = __builtin_amdgcn_mfma_f32_16x16x32_bf16(AHl1, BH1,  acc[mf], 0,0,0);
      }
    }
  }

  #pragma unroll
  for (int mf=0; mf<2; ++mf){
    int cc = w*8 + mf*4 + lk;
    int wi = cc*1024 + px;
    size_t sidx = ((size_t)(b*64 + cc))*1024 + px;
    float cprev = cst[sidx];
    float ic = acc[mf][0] + smalls[O_CB + cc];
    float fc = acc[mf][1] + smalls[O_CB + 64 + cc];
    float gc = acc[mf][2] + smalls[O_CB + 128 + cc];
    float oc = acc[mf][3] + smalls[O_CB + 192 + cc];
    float ig = sigm(ic + smalls[O_WCI + wi]*cprev);
    float fg = sigm(fc + smalls[O_WCF + wi]*cprev);
    float cnew = fg*cprev + ig*tanhc(gc);
    float og = sigm(oc + smalls[O_WCO + wi]*cnew);
    cst[sidx]  = cnew;
    hnew[sidx] = og*tanhc(cnew);
  }
}

// ---------------------------------------------------------------------------
// 1x1 projections -> bf16 MFMA-ready buffers.
// grid (128 ntiles of 8, 4 b) = 512 blocks (2/CU), block 256
// ---------------------------------------------------------------------------
__global__ __launch_bounds__(256) void k_proj(
  const float* __restrict__ hnew, const float* __restrict__ mst,
  const float* __restrict__ smalls,
  ushort* __restrict__ qb16, ushort* __restrict__ khb16, ushort* __restrict__ kmb16,
  ushort* __restrict__ vth16, ushort* __restrict__ vtm16)
{
  __shared__ float hs[64*9];
  __shared__ float ms[64*9];
  int b = blockIdx.y, n0 = blockIdx.x*8;
  int tid = threadIdx.x, nl = tid&7, rg = tid>>3;
  for (int idx = tid; idx < 512; idx += 256){
    int nn = idx & 7, ch = idx >> 3;
    hs[ch*9+nn] = hnew[((size_t)b*64+ch)*1024 + n0 + nn];
    ms[ch*9+nn] = mst [((size_t)b*64+ch)*1024 + n0 + nn];
  }
  __syncthreads();
  int n = n0 + nl;
  for (int j = 0; j < 6; ++j){
    int r = rg + 32*j;
    if (r >= 176) break;
    const float* src; const float* wrow; float bias;
    int mode, rr;
    if (r < 16)      { mode=0; rr=r;     src = hs; wrow = smalls+O_QW  + rr*64; bias = smalls[O_QB+rr]; }
    else if (r < 32) { mode=1; rr=r-16;  src = hs; wrow = smalls+O_KW  + rr*64; bias = smalls[O_KB+rr]; }
    else if (r < 48) { mode=2; rr=r-32;  src = ms; wrow = smalls+O_K2W + rr*64; bias = smalls[O_K2B+rr]; }
    else if (r < 112){ mode=3; rr=r-48;  src = hs; wrow = smalls+O_VW  + rr*64; bias = smalls[O_VB+rr]; }
    else             { mode=4; rr=r-112; src = ms; wrow = smalls+O_V2W + rr*64; bias = smalls[O_V2B+rr]; }
    float acc = bias;
    #pragma unroll
    for (int c4 = 0; c4 < 16; ++c4){
      float4 w4 = *reinterpret_cast<const float4*>(wrow + c4*4);
      acc += w4.x*src[(c4*4+0)*9+nl] + w4.y*src[(c4*4+1)*9+nl]
           + w4.z*src[(c4*4+2)*9+nl] + w4.w*src[(c4*4+3)*9+nl];
    }
    ushort v = f2bu(acc);
    if (mode <= 2){
      ushort* base = (mode==0) ? qb16 : (mode==1) ? khb16 : kmb16;
      size_t o = ((size_t)b*1024 + n)*32;
      base[o + rr] = v;
      base[o + 16 + rr] = 0;
    } else {
      ushort* base = (mode==3) ? vth16 : vtm16;
      base[((size_t)b*64 + rr)*1024 + n] = v;
    }
  }
}

// ---------------------------------------------------------------------------
// MFMA flash attention. grid (64 ntiles of 16, 4 b, 2 br) = 512 blocks (2/CU),
// block 256 = 4 waves.
// ---------------------------------------------------------------------------
__global__ __launch_bounds__(256) void k_fatt(
  const ushort* __restrict__ qb16, const ushort* __restrict__ khb16,
  const ushort* __restrict__ kmb16, const ushort* __restrict__ vth16,
  const ushort* __restrict__ vtm16, float* __restrict__ zcat)
{
  __shared__ ushort es[16*272];
  __shared__ float rs_s[4][16];
  int n0 = blockIdx.x*16, b = blockIdx.y, br = blockIdx.z;
  const ushort* kb = (br ? kmb16 : khb16) + (size_t)b*32768;
  const ushort* vt = (br ? vtm16 : vth16) + (size_t)b*65536;
  const ushort* qp = qb16 + (size_t)b*32768;
  int tid = threadIdx.x;
  int w = tid >> 6, lane = tid & 63, lr = lane & 15, lk = lane >> 4;
  const float4v Z4 = {0.f,0.f,0.f,0.f};

  short8v qf = ldfrag(qp + (size_t)(n0 + lr)*32 + lk*8);

  float4v acc[2];
  acc[0]=Z4; acc[1]=Z4;
  float rsum = 0.f;

  #pragma unroll 1
  for (int mc = 0; mc < 4; ++mc){
    int mbase = mc*256 + w*64;
    #pragma unroll
    for (int tau = 0; tau < 4; ++tau){
      short8v af = ldfrag(kb + (size_t)(mbase + tau*16 + lr)*32 + lk*8);
      float4v d = __builtin_amdgcn_mfma_f32_16x16x32_bf16(af, qf, Z4, 0,0,0);
      ushort u0 = f2bu(__expf(fminf(d[0], 60.f)));
      ushort u1 = f2bu(__expf(fminf(d[1], 60.f)));
      ushort u2 = f2bu(__expf(fminf(d[2], 60.f)));
      ushort u3 = f2bu(__expf(fminf(d[3], 60.f)));
      rsum += (bu2f(u0) + bu2f(u1)) + (bu2f(u2) + bu2f(u3));
      unsigned lo = (unsigned)u0 | ((unsigned)u1 << 16);
      unsigned hi = (unsigned)u2 | ((unsigned)u3 << 16);
      *reinterpret_cast<uint2*>(&es[lr*272 + w*64 + tau*16 + lk*4]) = make_uint2(lo, hi);
    }
    __syncthreads();
    #pragma unroll
    for (int ks = 0; ks < 8; ++ks){
      short8v av = ldfrag(vt + (size_t)(w*16 + lr)*1024 + mc*256 + ks*32 + lk*8);
      short8v bv = ldfrag(&es[lr*272 + ks*32 + lk*8]);
      acc[ks & 1] = __builtin_amdgcn_mfma_f32_16x16x32_bf16(av, bv, acc[ks & 1], 0,0,0);
    }
    __syncthreads();
  }

  {
    float r = rsum;
    r += __shfl_xor(r, 16);
    r += __shfl_xor(r, 32);
    if (lane < 16) rs_s[w][lr] = r;
  }
  __syncthreads();
  {
    float rinv = 1.0f / (rs_s[0][lr] + rs_s[1][lr] + rs_s[2][lr] + rs_s[3][lr]);
    #pragma unroll
    for (int r = 0; r < 4; ++r){
      int c = w*16 + lk*4 + r;
      zcat[((size_t)(b*128 + br*64 + c))*1024 + n0 + lr] = (acc[0][r] + acc[1][r])*rinv;
    }
  }
}

// ---------------------------------------------------------------------------
// zcomb: zt = zwT^T@zcat+z_b; comb = mw4@[zt;hnew]+m_b; gate; h_out
// writes m state, hT_hi/lo bf16, and d_out
// ---------------------------------------------------------------------------
__global__ __launch_bounds__(256) void k_zcomb(
  const float* __restrict__ zcat, const float* __restrict__ hnew,
  const float* __restrict__ smalls, const float* __restrict__ zwT,
  const float* __restrict__ mw4, const int* __restrict__ flagp,
  float* __restrict__ mst, ushort* __restrict__ hth, ushort* __restrict__ htl,
  void* __restrict__ outraw, int t)
{
  __shared__ float zin[128*9];
  __shared__ float hl [64*9];
  __shared__ float ml [64*9];
  __shared__ float zt_s[8*132];
  __shared__ float ho_s[64*9];
  __shared__ float mn_s[64*9];
  int n0 = blockIdx.x*8, b = blockIdx.y;
  int tid = threadIdx.x;
  int px = tid >> 5, lr = tid & 31;
  int flag = *flagp;
  for (int idx = tid; idx < 1024; idx += 256){
    int ch = idx >> 3, pp = idx & 7;
    zin[ch*9+pp] = zcat[((size_t)b*128 + ch)*1024 + n0 + pp];
  }
  for (int idx = tid; idx < 512; idx += 256){
    int ch = idx >> 3, pp = idx & 7;
    hl[ch*9+pp] = hnew[((size_t)b*64 + ch)*1024 + n0 + pp];
    ml[ch*9+pp] = mst [((size_t)b*64 + ch)*1024 + n0 + pp];
  }
  __syncthreads();
  {
    float4 a4 = *reinterpret_cast<const float4*>(&smalls[O_ZB + lr*4]);
    float acc0=a4.x, acc1=a4.y, acc2=a4.z, acc3=a4.w;
    #pragma unroll 4
    for (int k = 0; k < 128; ++k){
      float zv = zin[k*9 + px];
      float4 w4 = *reinterpret_cast<const float4*>(&zwT[k*128 + lr*4]);
      acc0 += w4.x*zv; acc1 += w4.y*zv; acc2 += w4.z*zv; acc3 += w4.w*zv;
    }
    *reinterpret_cast<float4*>(&zt_s[px*132 + lr*4]) = make_float4(acc0,acc1,acc2,acc3);
  }
  __syncthreads();
  {
    float acc6[6];
    #pragma unroll
    for (int i=0;i<6;++i) acc6[i] = smalls[O_MB + lr + 32*i];
    #pragma unroll 2
    for (int k4 = 0; k4 < 32; ++k4){
      float4 xv = *reinterpret_cast<const float4*>(&zt_s[px*132 + k4*4]);
      const float* wb = mw4 + (size_t)(k4*192)*4;
      #pragma unroll
      for (int i=0;i<6;++i){
        float4 w = *reinterpret_cast<const float4*>(&wb[(lr + 32*i)*4]);
        acc6[i] += w.x*xv.x + w.y*xv.y + w.z*xv.z + w.w*xv.w;
      }
    }
    #pragma unroll 2
    for (int k4 = 32; k4 < 48; ++k4){
      int ch = (k4-32)*4;
      float4 xv = make_float4(hl[ch*9+px], hl[(ch+1)*9+px], hl[(ch+2)*9+px], hl[(ch+3)*9+px]);
      const float* wb = mw4 + (size_t)(k4*192)*4;
      #pragma unroll
      for (int i=0;i<6;++i){
        float4 w = *reinterpret_cast<const float4*>(&wb[(lr + 32*i)*4]);
        acc6[i] += w.x*xv.x + w.y*xv.y + w.z*xv.z + w.w*xv.w;
      }
    }
    #pragma unroll
    for (int j=0;j<2;++j){
      int ch = lr + 32*j;
      float mold = ml[ch*9 + px];
      float gi = sigm(acc6[4+j]);
      float mnew = (1.0f-gi)*mold + gi*tanhc(acc6[2+j]);
      float ho = sigm(acc6[j])*mnew;
      ho_s[ch*9+px] = ho;
      mn_s[ch*9+px] = mnew;
    }
  }
  __syncthreads();
  for (int idx = tid; idx < 512; idx += 256){
    int ch = idx >> 3, pp = idx & 7;
    int n = n0 + pp;
    size_t gidx = ((size_t)b*64 + ch)*1024 + n;
    mst[gidx] = mn_s[ch*9+pp];
    float ho = ho_s[ch*9+pp];
    size_t tix = ((size_t)b*1024 + n)*64 + ch;
    ushort hb_ = f2bu(ho);
    hth[tix] = hb_;
    htl[tix] = f2bu(ho - bu2f(hb_));
    size_t oidx = ((size_t)(b*64+ch)*8 + t)*1024 + n;
    if (flag) ((float*)outraw)[oidx] = ho;
    else      ((bf16*)outraw)[oidx] = __float2bfloat16(ho);
  }
}

extern "C" void kernel_launch(void* const* d_in, const int* in_sizes, int n_in,
                              void* d_out, int out_size, void* d_ws, size_t ws_size,
                              hipStream_t stream)
{
  float* ws = (float*)d_ws;
  int* flag = (int*)(ws + WS_FLAG);
  float* c    = ws + WS_C;
  float* m    = ws + WS_M;
  float* hnew = ws + WS_HNEW;
  float* zcat = ws + WS_ZCAT;
  float* zwT  = ws + WS_ZWT;
  float* mw4  = ws + WS_MW4;
  ushort* qb16  = (ushort*)(ws + WS_QB16);
  ushort* khb16 = (ushort*)(ws + WS_KHB16);
  ushort* kmb16 = (ushort*)(ws + WS_KMB16);
  ushort* vth16 = (ushort*)(ws + WS_VTH16);
  ushort* vtm16 = (ushort*)(ws + WS_VTM16);
  ushort* wa_hi = (ushort*)(ws + WS_WAHI);
  ushort* wa_lo = (ushort*)(ws + WS_WALO);
  ushort* xt_hi = (ushort*)(ws + WS_XTHI);
  ushort* xt_lo = (ushort*)(ws + WS_XTLO);
  ushort* ht_hi = (ushort*)(ws + WS_HTHI);
  ushort* ht_lo = (ushort*)(ws + WS_HTLO);

  k_probe<<<1, 256, 0, stream>>>((const unsigned int*)d_in[0], flag);
  P18 pk;
  for (int i = 0; i < 18; ++i) pk.p[i] = d_in[2 + i];
  k_wconv<<<dim3(64,18), 256, 0, stream>>>(pk, flag, ws);
  k_init<<<3072, 256, 0, stream>>>(d_in[1], flag, ws);
  k_xt<<<dim3(16,32), 256, 0, stream>>>(d_in[0], flag, ws);
  k_wtrans<<<144, 256, 0, stream>>>(ws);

  for (int t = 0; t < 8; ++t){
    k_conv_mfma<<<dim3(64,4), 512, 0, stream>>>(flag, wa_hi, wa_lo, xt_hi, xt_lo,
                                                ht_hi, ht_lo, ws, c, hnew, t);
    k_proj<<<dim3(128,4), 256, 0, stream>>>(hnew, m, ws, qb16, khb16, kmb16, vth16, vtm16);
    k_fatt<<<dim3(64,4,2), 256, 0, stream>>>(qb16, khb16, kmb16, vth16, vtm16, zcat);
    k_zcomb<<<dim3(128,4), 256, 0, stream>>>(zcat, hnew, ws, zwT, mw4, flag,
                                             m, ht_hi, ht_lo, d_out, t);
  }
  (void)in_sizes; (void)n_in; (void)out_size; (void)ws_size;
}